// Round 1
// 1345.601 us; speedup vs baseline: 1.0054x; 1.0054x over previous
//
#include <hip/hip_runtime.h>
#include <hip/hip_bf16.h>
#include <hip/hip_fp16.h>
#include <stdint.h>

typedef __hip_bfloat16 bf16;
using bf16x8 = __attribute__((ext_vector_type(8))) short;     // 8 bf16
using half8  = __attribute__((ext_vector_type(8))) _Float16;  // 8 fp16
using f32x4  = __attribute__((ext_vector_type(4))) float;

#define S_LEN   4096
#define HID_    2048
#define NH_     16
#define D_      128
#define C_      1024
#define SCALE_  0.08838834764831845f   // 1/sqrt(128)
#define DESC_   (1.0 / 1048576.0)      // 2^-20 (undo ×1024 on both operands)

__device__ __forceinline__ float bflo(uint32_t u) {
  uint32_t x = (u & 0xffffu) << 16; float f; __builtin_memcpy(&f, &x, 4); return f;
}
__device__ __forceinline__ float bfhi(uint32_t u) {
  uint32_t x = u & 0xffff0000u; float f; __builtin_memcpy(&f, &x, 4); return f;
}
__device__ __forceinline__ void storeC(float* p, float v) { *p = v; }
__device__ __forceinline__ void storeC(bf16* p, float v)  { *p = __float2bfloat16(v); }
__device__ __forceinline__ void split2(float x, _Float16& h, _Float16& l) {
  h = (_Float16)x; l = (_Float16)(x - (float)h);
}

// ---------------- fp32 -> bf16 convert (hidden) ----------------
__global__ __launch_bounds__(256) void cvt_k(const float* __restrict__ src, bf16* __restrict__ dst) {
  int i = (blockIdx.x * 256 + threadIdx.x) * 4;
  float4 v = *(const float4*)(src + i);
  bf16 o[4] = {__float2bfloat16(v.x), __float2bfloat16(v.y),
               __float2bfloat16(v.z), __float2bfloat16(v.w)};
  *(uint2*)(dst + i) = *(uint2*)o;
}

// ---------------- fp32 -> fp16 hi/lo split (x1024), contiguous ----------------
__global__ __launch_bounds__(256) void split_q_k(const float* __restrict__ src,
                                                 _Float16* __restrict__ oh, _Float16* __restrict__ ol) {
  int i = (blockIdx.x * 256 + threadIdx.x) * 4;
  float4 v = *(const float4*)(src + i);
  float xs[4] = {v.x, v.y, v.z, v.w};
  _Float16 hh[4], ll[4];
#pragma unroll
  for (int e = 0; e < 4; ++e) split2(xs[e] * 1024.0f, hh[e], ll[e]);
  *(uint2*)(oh + i) = *(uint2*)hh;
  *(uint2*)(ol + i) = *(uint2*)ll;
}

// ---------------- ck split: ckvF rows (stride 256, first 128 cols) -> [c][k] fp16 hi/lo ----------------
__global__ __launch_bounds__(256) void split_ck_k(const float* __restrict__ ckvF,
                                                  _Float16* __restrict__ oh, _Float16* __restrict__ ol) {
  int idx = blockIdx.x * 256 + threadIdx.x;     // c*128 + k, total 131072
  int c = idx >> 7, k = idx & 127;
  float x = ckvF[(size_t)c * 256 + k] * 1024.0f;
  _Float16 h, l; split2(x, h, l);
  oh[idx] = h; ol[idx] = l;
}

// ---------------- transpose: fp32 (R x N) -> bf16 (N x R) ----------------
__global__ __launch_bounds__(256) void transpose_k(const float* __restrict__ src,
                                                   bf16* __restrict__ dst, int R, int N) {
  __shared__ float tile[64][65];
  const int c0 = blockIdx.x * 64, r0 = blockIdx.y * 64;
  const int t = threadIdx.x, cc = t & 63, rb = t >> 6;
#pragma unroll
  for (int i = 0; i < 16; ++i) {
    int r = rb + i * 4;
    tile[r][cc] = src[(size_t)(r0 + r) * N + c0 + cc];
  }
  __syncthreads();
#pragma unroll
  for (int i = 0; i < 16; ++i) {
    int r = rb + i * 4;
    dst[(size_t)(c0 + r) * R + r0 + cc] = __float2bfloat16(tile[cc][r]);
  }
}

// ---------------- transpose: fp32 (R x N) -> fp32 (N x R), prescaled x1024 ----------------
__global__ __launch_bounds__(256) void trans_f32s(const float* __restrict__ src,
                                                  float* __restrict__ dst, int R, int N) {
  __shared__ float tile[64][65];
  const int c0 = blockIdx.x * 64, r0 = blockIdx.y * 64;
  const int t = threadIdx.x, cc = t & 63, rb = t >> 6;
#pragma unroll
  for (int i = 0; i < 16; ++i) {
    int r = rb + i * 4;
    tile[r][cc] = src[(size_t)(r0 + r) * N + c0 + cc];
  }
  __syncthreads();
#pragma unroll
  for (int i = 0; i < 16; ++i) {
    int r = rb + i * 4;
    dst[(size_t)(c0 + r) * R + r0 + cc] = tile[cc][r] * 1024.0f;
  }
}

// ---------------- bias concat ----------------
__global__ void build_bias(const float* bq, const float* blk, const float* blv,
                           const float* bk, const float* bv, const float* bo,
                           float* bQ, float* bLKLV, float* bKV, float* bO) {
  int i = blockIdx.x * 256 + threadIdx.x;
  if (i < 2048)       bQ[i] = bq[i];
  else if (i < 6144)  { int j = i - 2048; bLKLV[j] = (j < 2048) ? blk[j] : blv[j - 2048]; }
  else if (i < 6400)  { int j = i - 6144; bKV[j] = (j < 128) ? bk[j] : bv[j - 128]; }
  else if (i < 8448)  bO[i - 6400] = bo[i - 6400];
}

// ---------------- plain m97-style bf16 GEMM ----------------
template <typename OutT>
__global__ __launch_bounds__(256) void gemm_bt(const bf16* __restrict__ A, const bf16* __restrict__ BT,
                                               const float* __restrict__ bias, OutT* __restrict__ Cmat,
                                               int M, int N, int K, int lda) {
  __shared__ bf16 As[128 * 32];
  __shared__ bf16 Bs[128 * 32];
  const int t = threadIdx.x;
  const int wave = t >> 6, lane = t & 63;
  const int wr = wave >> 1, wc = wave & 1;
  const int quad = lane >> 4, l15 = lane & 15;
  const int bx = blockIdx.x * 128, by = blockIdx.y * 128;
  const int srow = t >> 2, scol = (t & 3) * 8;
  f32x4 acc[4][4] = {};
  const bf16* a0 = A + (size_t)(by + srow) * lda + scol;
  const bf16* a1 = A + (size_t)(by + 64 + srow) * lda + scol;
  const bf16* b0 = BT + (size_t)(bx + srow) * K + scol;
  const bf16* b1 = BT + (size_t)(bx + 64 + srow) * K + scol;
  for (int k0 = 0; k0 < K; k0 += 32) {
    __builtin_amdgcn_global_load_lds((const __attribute__((address_space(1))) void*)(a0 + k0),
                                     (__attribute__((address_space(3))) void*)(As + t * 8), 16, 0, 0);
    __builtin_amdgcn_global_load_lds((const __attribute__((address_space(1))) void*)(a1 + k0),
                                     (__attribute__((address_space(3))) void*)(As + 2048 + t * 8), 16, 0, 0);
    __builtin_amdgcn_global_load_lds((const __attribute__((address_space(1))) void*)(b0 + k0),
                                     (__attribute__((address_space(3))) void*)(Bs + t * 8), 16, 0, 0);
    __builtin_amdgcn_global_load_lds((const __attribute__((address_space(1))) void*)(b1 + k0),
                                     (__attribute__((address_space(3))) void*)(Bs + 2048 + t * 8), 16, 0, 0);
    __syncthreads();
    bf16x8 aF[4], bF[4];
#pragma unroll
    for (int i = 0; i < 4; ++i)
      aF[i] = *(const bf16x8*)(As + (wr * 64 + i * 16 + l15) * 32 + quad * 8);
#pragma unroll
    for (int j = 0; j < 4; ++j)
      bF[j] = *(const bf16x8*)(Bs + (wc * 64 + j * 16 + l15) * 32 + quad * 8);
#pragma unroll
    for (int i = 0; i < 4; ++i)
#pragma unroll
      for (int j = 0; j < 4; ++j)
        acc[i][j] = __builtin_amdgcn_mfma_f32_16x16x32_bf16(aF[i], bF[j], acc[i][j], 0, 0, 0);
    __syncthreads();
  }
#pragma unroll
  for (int i = 0; i < 4; ++i)
#pragma unroll
    for (int j = 0; j < 4; ++j)
#pragma unroll
      for (int r = 0; r < 4; ++r) {
        int row = by + wr * 64 + i * 16 + quad * 4 + r;
        int col = bx + wc * 64 + j * 16 + l15;
        storeC(&Cmat[(size_t)row * N + col], acc[i][j][r] + bias[col]);
      }
}

// ---------------- precise GEMM: fp16 2-way split, 4 MFMA terms, fp64 per-kstep accum ----------------
__global__ __launch_bounds__(256) void gemm_prec4(const float* __restrict__ A, const float* __restrict__ BT,
                                                  const float* __restrict__ bias, float* __restrict__ Cmat,
                                                  int M, int N, int K, int lda) {
  __shared__ _Float16 Ah[128 * 32], Al[128 * 32], Bh[128 * 32], Bl[128 * 32];
  const int t = threadIdx.x;
  const int wave = t >> 6, lane = t & 63;
  const int wr = wave >> 1, wc = wave & 1;
  const int quad = lane >> 4, l15 = lane & 15;
  const int bx = blockIdx.x * 128, by = blockIdx.y * 128;
  double acc[4][4][4] = {};
  for (int k0 = 0; k0 < K; k0 += 32) {
#pragma unroll
    for (int it = 0; it < 4; ++it) {
      int sl = t + it * 256;
      int isB = sl >> 9, s2 = sl & 511, r = s2 >> 2, g = s2 & 3;
      const float* src = isB ? (BT + (size_t)(bx + r) * K + k0 + g * 8)
                             : (A  + (size_t)(by + r) * lda + k0 + g * 8);
      float4 u = ((const float4*)src)[0];
      float4 v = ((const float4*)src)[1];
      float xs[8] = {u.x, u.y, u.z, u.w, v.x, v.y, v.z, v.w};
      half8 hh, ll;
#pragma unroll
      for (int e = 0; e < 8; ++e) {
        float x = isB ? xs[e] : xs[e] * 1024.0f;
        _Float16 h, l; split2(x, h, l);
        hh[e] = h; ll[e] = l;
      }
      _Float16* dh = (isB ? Bh : Ah) + r * 32 + g * 8;
      _Float16* dl = (isB ? Bl : Al) + r * 32 + g * 8;
      *(half8*)dh = hh;
      *(half8*)dl = ll;
    }
    __syncthreads();
    half8 aFh[4], aFl[4], bFh[4], bFl[4];
#pragma unroll
    for (int i = 0; i < 4; ++i) {
      int ro = (wr * 64 + i * 16 + l15) * 32 + quad * 8;
      aFh[i] = *(const half8*)(Ah + ro);
      aFl[i] = *(const half8*)(Al + ro);
    }
#pragma unroll
    for (int j = 0; j < 4; ++j) {
      int ro = (wc * 64 + j * 16 + l15) * 32 + quad * 8;
      bFh[j] = *(const half8*)(Bh + ro);
      bFl[j] = *(const half8*)(Bl + ro);
    }
#pragma unroll
    for (int i = 0; i < 4; ++i)
#pragma unroll
      for (int j = 0; j < 4; ++j) {
        f32x4 tt = {0.f, 0.f, 0.f, 0.f};
        tt = __builtin_amdgcn_mfma_f32_16x16x32_f16(aFl[i], bFl[j], tt, 0, 0, 0);
        tt = __builtin_amdgcn_mfma_f32_16x16x32_f16(aFl[i], bFh[j], tt, 0, 0, 0);
        tt = __builtin_amdgcn_mfma_f32_16x16x32_f16(aFh[i], bFl[j], tt, 0, 0, 0);
        tt = __builtin_amdgcn_mfma_f32_16x16x32_f16(aFh[i], bFh[j], tt, 0, 0, 0);
#pragma unroll
        for (int r = 0; r < 4; ++r) acc[i][j][r] += (double)tt[r];
      }
    __syncthreads();
  }
#pragma unroll
  for (int i = 0; i < 4; ++i)
#pragma unroll
    for (int j = 0; j < 4; ++j)
#pragma unroll
      for (int r = 0; r < 4; ++r) {
        int row = by + wr * 64 + i * 16 + quad * 4 + r;
        int col = bx + wc * 64 + j * 16 + l15;
        Cmat[(size_t)row * N + col] = (float)(acc[i][j][r] * DESC_ + (double)bias[col]);
      }
}

// ---------------- fp64 rmsnorm + fp32-faithful rope, fp32 buffer in place ----------------
__global__ __launch_bounds__(256) void normrope64(float* __restrict__ base, const float* __restrict__ w,
                                                  int nRows, int hPerS, int sStride,
                                                  int posMul, int posAdd) {
  int row = blockIdx.x * 4 + (threadIdx.x >> 6);
  int lane = threadIdx.x & 63;
  if (row >= nRows) return;
  int s = row / hPerS, h = row - s * hPerS;
  float* p = base + (size_t)s * sStride + h * 128;
  double x0 = (double)p[lane];
  double x1 = (double)p[lane + 64];
  double ss = x0 * x0 + x1 * x1;
#pragma unroll
  for (int m = 32; m; m >>= 1) ss += __shfl_xor(ss, m, 64);
  double rstd = 1.0 / sqrt(ss * (1.0 / 128.0) + 1e-6);
  double n0 = x0 * rstd * (double)w[lane];
  double n1 = x1 * rstd * (double)w[lane + 64];
  double other = __shfl_xor(n0, 32, 64);
  int fi = lane & 31;
  float invf = 1.0f / (float)pow(10000.0, (double)fi * (1.0 / 32.0));
  float angf = (float)(s * posMul + posAdd) * invf;
  double ang = (double)angf;
  double cs = cos(ang), sn = sin(ang);
  double r0 = (lane < 32) ? (n0 * cs - other * sn) : (other * sn + n0 * cs);
  p[lane] = (float)r0;
  p[lane + 64] = (float)n1;
}

// ---------------- bf16 rmsnorm+rope (smooth lk path) ----------------
__global__ __launch_bounds__(256) void normrope_bf(bf16* __restrict__ base, const float* __restrict__ w,
                                                   int nRows, int hPerS, int sStride) {
  int row = blockIdx.x * 4 + (threadIdx.x >> 6);
  int lane = threadIdx.x & 63;
  if (row >= nRows) return;
  int s = row / hPerS, h = row - s * hPerS;
  bf16* p = base + (size_t)s * sStride + h * 128;
  float x0 = __bfloat162float(p[lane]);
  float x1 = __bfloat162float(p[lane + 64]);
  float ss = x0 * x0 + x1 * x1;
#pragma unroll
  for (int m = 32; m; m >>= 1) ss += __shfl_xor(ss, m, 64);
  float rstd = rsqrtf(ss * 0.0078125f + 1e-6f);
  float n0 = x0 * rstd * w[lane];
  float n1 = x1 * rstd * w[lane + 64];
  float other = __shfl_xor(n0, 32, 64);
  int fi = lane & 31;
  float invf = 1.0f / (float)pow(10000.0, (double)fi * (1.0 / 32.0));
  float ang = (float)s * invf;
  float cs = cosf(ang), sn = sinf(ang);
  float r0 = (lane < 32) ? (n0 * cs - other * sn) : (other * sn + n0 * cs);
  p[lane] = __float2bfloat16(r0);
  p[lane + 64] = __float2bfloat16(n1);
}

// ---------------- compress logits (fp64) ----------------
__global__ __launch_bounds__(256) void wlog_k(const float* __restrict__ hidden, const float* __restrict__ wcmp,
                                              const float* __restrict__ bcmp, float* __restrict__ wlog) {
  int s = blockIdx.x * 4 + (threadIdx.x >> 6);
  int lane = threadIdx.x & 63;
  const float* hp = hidden + (size_t)s * HID_;
  double acc = 0.0;
  for (int i = lane; i < HID_; i += 64)
    acc += (double)hp[i] * (double)wcmp[i];
#pragma unroll
  for (int m = 32; m; m >>= 1) acc += __shfl_xor(acc, m, 64);
  if (lane == 0) wlog[s] = (float)(acc + (double)bcmp[0]);
}

__global__ void wsm_k(const float* __restrict__ wlog, float* __restrict__ wsm) {
  int c = blockIdx.x * 256 + threadIdx.x;
  if (c >= C_) return;
  double v[4], m = -1e300;
#pragma unroll
  for (int r = 0; r < 4; ++r) { v[r] = (double)wlog[4 * c + r]; if (v[r] > m) m = v[r]; }
  double sum = 0.0;
#pragma unroll
  for (int r = 0; r < 4; ++r) { v[r] = exp(v[r] - m); sum += v[r]; }
#pragma unroll
  for (int r = 0; r < 4; ++r) wsm[4 * c + r] = (float)(v[r] / sum);
}

__global__ __launch_bounds__(256) void entries_k(const float* __restrict__ hidden, const float* __restrict__ wsm,
                                                 float* __restrict__ entriesF) {
  int idx = blockIdx.x * 256 + threadIdx.x;     // c*2048 + hcol
  int c = idx >> 11, hcol = idx & 2047;
  double e = 0.0;
#pragma unroll
  for (int r = 0; r < 4; ++r)
    e += (double)wsm[4 * c + r] * (double)hidden[(size_t)(4 * c + r) * HID_ + hcol];
  entriesF[idx] = (float)e;
}

// ---------------- sparse v8: 8 queries x 2 heads per block, 16 waves ----------------
// Phase 1 identical to v7 (A rows 0-7 = head 2*by, rows 8-15 = head 2*by+1) but tiles
// spread over 16 waves. Phase 2: ONE (query, head) chain per wave (w>>3 = head parity,
// w&7 = query). 64 KB LDS + 1024 threads -> 2 blocks/CU = 32 waves/CU (100% occupancy,
// was 50%). Selection uses a per-lane top-2 cache: each round is butterfly-only; the
// 16-candidate rescan fires only when a lane wins a second time (execz-skipped usually).
// jmax limits all scans to the causally valid tiles (avg ~8.5 of 16).
__global__ __launch_bounds__(1024, 8) void sparse_v8(const _Float16* __restrict__ qh, const _Float16* __restrict__ ql,
                                                     const _Float16* __restrict__ ckh, const _Float16* __restrict__ ckl,
                                                     const float* __restrict__ ckvF, bf16* __restrict__ sp) {
  __shared__ float sc[16 * 1024];               // 64 KB -> 2 blocks/CU (32 waves)
  const int by = blockIdx.y;                    // head pair: heads 2*by, 2*by+1
  const int s0 = blockIdx.x * 8;
  const int t = threadIdx.x, w = t >> 6, lane = t & 63;
  const int quad = lane >> 4, l15 = lane & 15;
  // A row m: query s0+(m&7), head 2*by+(m>>3)
  const int sA = s0 + (l15 & 7);
  const int hA = 2 * by + (l15 >> 3);
  half8 aFh[4], aFl[4];
  {
    const _Float16* qbh = qh + (size_t)sA * HID_ + hA * 128 + quad * 8;
    const _Float16* qbl = ql + (size_t)sA * HID_ + hA * 128 + quad * 8;
#pragma unroll
    for (int kk = 0; kk < 4; ++kk) {
      aFh[kk] = *(const half8*)(qbh + kk * 32);
      aFl[kk] = *(const half8*)(qbl + kk * 32);
    }
  }
  const int nvmax  = (s0 >> 2) + 2;             // max causally valid blocks for s in [s0,s0+8)
  const int ntiles = (nvmax + 15) >> 4;
  const double esc = (double)SCALE_ * DESC_;
  for (int ct = w; ct < ntiles; ct += 16) {
    const int c0 = ct * 16;
    const _Float16* kbh = ckh + (size_t)(c0 + l15) * 128 + quad * 8;
    const _Float16* kbl = ckl + (size_t)(c0 + l15) * 128 + quad * 8;
    double a64[4] = {0.0, 0.0, 0.0, 0.0};
#pragma unroll
    for (int kk = 0; kk < 4; ++kk) {
      half8 bh = *(const half8*)(kbh + kk * 32);
      half8 bl = *(const half8*)(kbl + kk * 32);
      f32x4 tt = {0.f, 0.f, 0.f, 0.f};
      tt = __builtin_amdgcn_mfma_f32_16x16x32_f16(aFl[kk], bl, tt, 0, 0, 0);
      tt = __builtin_amdgcn_mfma_f32_16x16x32_f16(aFl[kk], bh, tt, 0, 0, 0);
      tt = __builtin_amdgcn_mfma_f32_16x16x32_f16(aFh[kk], bl, tt, 0, 0, 0);
      tt = __builtin_amdgcn_mfma_f32_16x16x32_f16(aFh[kk], bh, tt, 0, 0, 0);
#pragma unroll
      for (int r = 0; r < 4; ++r) a64[r] += (double)tt[r];
    }
#pragma unroll
    for (int r = 0; r < 4; ++r)                 // all 16 C rows are real (q, head) pairs
      sc[(quad * 4 + r) * 1024 + c0 + l15] = (float)(a64[r] * esc);
  }
  __syncthreads();
  // ---- phase 2: wave w -> chain (head parity p = w>>3, query s0 + (w&7)) ----
  const int p = w >> 3, wq = w & 7;
  const int s = s0 + wq;
  const int nv = (s >= 3) ? (((s - 3) >> 2) + 1) : 0;
  const int jmax = (nv + 63) >> 6;              // wave-uniform valid j-tile count (0..16)
  const float* srow = sc + (p * 8 + wq) * 1024 + lane;
  // initial per-lane top-2 over valid candidates (strict > keeps lowest c on ties)
  float v1 = -1e38f, v2 = -1e38f; int i1 = 0x40000000, i2 = 0x40000000;
  for (int j = 0; j < jmax; ++j) {
    int c = j * 64 + lane;
    float v = (c < nv) ? srow[j * 64] : -1e38f;
    if (v > v1)      { v2 = v1; i2 = i1; v1 = v; i1 = c; }
    else if (v > v2) { v2 = v; i2 = c; }
  }
  uint32_t dead = 0u;
  bool need2 = false;                           // true: v2/i2 stale (consumed, not refilled)
  float bvs[8]; int bis[8];
#pragma unroll
  for (int it = 0; it < 8; ++it) {
    float bv = v1; int bi = i1;
#pragma unroll
    for (int mm = 32; mm; mm >>= 1) {
      float ov = __shfl_xor(bv, mm, 64);
      int   oi = __shfl_xor(bi, mm, 64);
      if (ov > bv || (ov == bv && oi < bi)) { bv = ov; bi = oi; }  // max value, lowest index
    }
    bvs[it] = bv; bis[it] = bi;
    if (bv > -1e29f && (bi & 63) == lane) {     // this lane owned the global winner
      dead |= 1u << (i1 >> 6);
      if (!need2) { v1 = v2; i1 = i2; need2 = true; }
      else {
        // second consecutive consumption: rescan alive candidates for a fresh top-2
        v1 = -1e38f; i1 = 0x40000000; v2 = -1e38f; i2 = 0x40000000;
        for (int j = 0; j < jmax; ++j) {
          if (!((dead >> j) & 1u)) {
            int c = j * 64 + lane;
            float v = (c < nv) ? srow[j * 64] : -1e38f;
            if (v > v1)      { v2 = v1; i2 = i1; v1 = v; i1 = c; }
            else if (v > v2) { v2 = v; i2 = c; }
          }
        }
        need2 = false;
      }
    }
  }
  // deferred gathers
  const float m = bvs[0];
  float esum = 0.f, cacc0 = 0.f, cacc1 = 0.f;
#pragma unroll
  for (int it = 0; it < 8; ++it) {
    if (bvs[it] > -1e29f) {
      float wgt = expf(bvs[it] - m);
      esum += wgt;
      const float* cvp = ckvF + (size_t)bis[it] * 256 + 128;
      cacc0 += wgt * cvp[lane];
      cacc1 += wgt * cvp[lane + 64];
    }
  }
  float inv = 1.0f / fmaxf(esum, 1e-9f);
  bf16* op = sp + (size_t)s * 2048 + (2 * by + p) * 128;
  op[lane] = __float2bfloat16(cacc0 * inv);
  op[lane + 64] = __float2bfloat16(cacc1 * inv);
}

// ---------------- local sliding-window (129 keys) + merge ----------------
__global__ __launch_bounds__(512) void local_k(const float* __restrict__ qf, const bf16* __restrict__ lklv,
                                               const bf16* __restrict__ sp, bf16* __restrict__ merged) {
  __shared__ uint32_t Ks[136 * 65];
  __shared__ float    Qs[8 * 128];
  __shared__ float    Ps[8 * 132];
  const int h = blockIdx.y;
  const int s0 = blockIdx.x * 8;
  const int t = threadIdx.x;
  const int kstart = (s0 >= 128) ? (s0 - 128) : 0;
  const int nrows = s0 + 8 - kstart;
  for (int idx = t; idx < nrows * 64; idx += 512) {
    int r = idx >> 6, c = idx & 63;
    Ks[r * 65 + c] = *(const uint32_t*)(lklv + (size_t)(kstart + r) * 4096 + h * 128 + c * 2);
  }
  for (int idx = t; idx < 1024; idx += 512) {
    int r = idx >> 7, c = idx & 127;
    Qs[idx] = qf[(size_t)(s0 + r) * HID_ + h * 128 + c];
  }
  __syncthreads();
  const int w = t >> 6, lane = t & 63;
  const int s = s0 + w;
  const int kq = (s >= 128) ? (s - 128) : 0;
  const int nk = s - kq + 1;
  const int koff = kq - kstart;
  const float* qrow = Qs + w * 128;
  float sv[3];
  float mloc = -1e30f;
  {
    int j = 0;
    for (int k = lane; k < nk; k += 64, ++j) {
      const uint32_t* kr = Ks + (koff + k) * 65;
      float dot = 0.f;
#pragma unroll 16
      for (int c = 0; c < 64; ++c) {
        uint32_t kp = kr[c];
        dot += qrow[2 * c] * bflo(kp) + qrow[2 * c + 1] * bfhi(kp);
      }
      float scv = dot * SCALE_;
      sv[j] = scv;
      mloc = fmaxf(mloc, scv);
    }
  }
#pragma unroll
  for (int mm = 32; mm; mm >>= 1) mloc = fmaxf(mloc, __shfl_xor(mloc, mm, 64));
  float lsum = 0.f;
  {
    int j = 0;
    for (int k = lane; k < nk; k += 64, ++j) {
      float e = expf(sv[j] - mloc);
      lsum += e;
      Ps[w * 132 + k] = e;
    }
  }
#pragma unroll
  for (int mm = 32; mm; mm >>= 1) lsum += __shfl_xor(lsum, mm, 64);
  __syncthreads();
  float c0 = 0.f, c1 = 0.f;
  const bf16* vbase = lklv + 2048 + h * 128 + lane * 2;
#pragma unroll 4
  for (int k = 0; k < nk; ++k) {
    float pw = Ps[w * 132 + k];
    uint32_t vp = *(const uint32_t*)(vbase + (size_t)(kq + k) * 4096);
    c0 += pw * bflo(vp);
    c1 += pw * bfhi(vp);
  }
  float inv = 1.0f / lsum;
  const bf16* spp = sp + (size_t)s * 2048 + h * 128 + lane * 2;
  bf16* mp = merged + (size_t)s * 2048 + h * 128 + lane * 2;
  float sp0 = __bfloat162float(spp[0]), sp1 = __bfloat162float(spp[1]);
  mp[0] = __float2bfloat16((c0 * inv + sp0) * 0.5f);
  mp[1] = __float2bfloat16((c1 * inv + sp1) * 0.5f);
}

// ---------------- host orchestration ----------------
extern "C" void kernel_launch(void* const* d_in, const int* in_sizes, int n_in,
                              void* d_out, int out_size, void* d_ws, size_t ws_size,
                              hipStream_t stream) {
  (void)in_sizes; (void)n_in; (void)out_size; (void)ws_size;
  const float* hidden = (const float*)d_in[0];
  const float* Wq   = (const float*)d_in[1];
  const float* bq   = (const float*)d_in[2];
  const float* Wcmp = (const float*)d_in[3];
  const float* bcmp = (const float*)d_in[4];
  const float* Wk   = (const float*)d_in[5];
  const float* bk   = (const float*)d_in[6];
  const float* Wv   = (const float*)d_in[7];
  const float* bv   = (const float*)d_in[8];
  const float* Wlk  = (const float*)d_in[9];
  const float* blk  = (const float*)d_in[10];
  const float* Wlv  = (const float*)d_in[11];
  const float* blv  = (const float*)d_in[12];
  const float* qn_w = (const float*)d_in[13];
  const float* kn_w = (const float*)d_in[14];
  const float* Wo   = (const float*)d_in[15];
  const float* bo   = (const float*)d_in[16];
  float* out = (float*)d_out;

  // workspace (~155 MB). Overlays: qh over WqTs (dead after q gemm), merged over hbf,
  // sp over bt_lklv (both dead after lklv gemm, which precedes sparse/local).
  char* ws = (char*)d_ws;
  float*    qf       = (float*)   (ws);                  // 33,554,432
  bf16*     lklv     = (bf16*)    (ws + 33554432);       // 33,554,432
  float*    WqTs     = (float*)   (ws + 67108864);       // 16,777,216 (x1024)
  _Float16* qh       = (_Float16*)(ws + 67108864);       // overlay of WqTs
  bf16*     hbf      = (bf16*)    (ws + 83886080);       // 16,777,216
  bf16*     merged   = (bf16*)    (ws + 83886080);       // overlay of hbf
  bf16*     bt_lklv  = (bf16*)    (ws + 100663296);      // 16,777,216
  bf16*     sp       = (bf16*)    (ws + 100663296);      // overlay of bt_lklv
  float*    WkvTs    = (float*)   (ws + 117440512);      //  2,097,152 (x1024)
  bf16*     WoT      = (bf16*)    (ws + 119537664);      //  8,388,608
  float*    entriesF = (float*)   (ws + 127926272);      //  8,388,608
  float*    ckvF     = (float*)   (ws + 136314880);      //  1,048,576
  _Float16* ckh      = (_Float16*)(ws + 137363456);      //    262,144
  _Float16* ckl      = (_Float16*)(ws + 137625600);      //    262,144
  float*    wlog     = (float*)   (ws + 137887744);      //     16,384
  float*    wsm      = (float*)   (ws + 137904128);      //     16,384
  float*    bQ       = (float*)   (ws + 137920512);      //      8,192
  float*    bLKLV    = (float*)   (ws + 137928704);      //     16,384
  float*    bKV      = (float*)   (ws + 137945088);      //      1,024
  float*    bO       = (float*)   (ws + 137946112);      //      8,192
  _Float16* ql       = (_Float16*)(ws + 137954304);      // 16,777,216  (end ~154.7 MB)

  cvt_k<<<dim3(8192), dim3(256), 0, stream>>>(hidden, hbf);

  trans_f32s<<<dim3(32, 32), dim3(256), 0, stream>>>(Wq, WqTs, HID_, HID_);
  trans_f32s<<<dim3(2, 32),  dim3(256), 0, stream>>>(Wk, WkvTs, HID_, 128);
  trans_f32s<<<dim3(2, 32),  dim3(256), 0, stream>>>(Wv, WkvTs + (size_t)128 * HID_, HID_, 128);
  transpose_k<<<dim3(32, 32), dim3(256), 0, stream>>>(Wlk, bt_lklv, HID_, HID_);
  transpose_k<<<dim3(32, 32), dim3(256), 0, stream>>>(Wlv, bt_lklv + (size_t)2048 * HID_, HID_, HID_);
  transpose_k<<<dim3(32, 32), dim3(256), 0, stream>>>(Wo, WoT, HID_, HID_);
  build_bias<<<dim3(33), dim3(256), 0, stream>>>(bq, blk, blv, bk, bv, bo, bQ, bLKLV, bKV, bO);

  wlog_k<<<dim3(1024), dim3(256), 0, stream>>>(hidden, Wcmp, bcmp, wlog);
  wsm_k<<<dim3(4), dim3(256), 0, stream>>>(wlog, wsm);
  entries_k<<<dim3(8192), dim3(256), 0, stream>>>(hidden, wsm, entriesF);

  // precise projections
  gemm_prec4<<<dim3(16, 32), dim3(256), 0, stream>>>(hidden,   WqTs,  bQ,  qf,   S_LEN, HID_, HID_, HID_);
  gemm_prec4<<<dim3(2, 8),   dim3(256), 0, stream>>>(entriesF, WkvTs, bKV, ckvF, C_,    256,  HID_, HID_);
  // smooth lk|lv projection (bf16)
  gemm_bt<bf16><<<dim3(32, 32), dim3(256), 0, stream>>>(hbf, bt_lklv, bLKLV, lklv, S_LEN, 4096, HID_, HID_);

  // norms + rope
  normrope64<<<dim3(16384), dim3(256), 0, stream>>>(qf,   qn_w, 65536, 16, HID_, 1, 0);
  normrope64<<<dim3(256),   dim3(256), 0, stream>>>(ckvF, kn_w, 1024,  1,  256,  4, 3);
  normrope_bf<<<dim3(16384), dim3(256), 0, stream>>>(lklv, kn_w, 65536, 16, 4096);

  // pre-split operands for sparse scores (after norms/rope; qh safely overlays dead WqTs)
  split_q_k<<<dim3(8192), dim3(256), 0, stream>>>(qf, qh, ql);
  split_ck_k<<<dim3(512), dim3(256), 0, stream>>>(ckvF, ckh, ckl);

  // attention branches (sparse: 8 head-pairs in y, 16 waves/block)
  sparse_v8<<<dim3(512, 8), dim3(1024), 0, stream>>>(qh, ql, ckh, ckl, ckvF, sp);
  local_k<<<dim3(512, 16), dim3(512), 0, stream>>>(qf, lklv, sp, merged);

  // output projection
  gemm_bt<float><<<dim3(16, 32), dim3(256), 0, stream>>>(merged, WoT, bO, out, S_LEN, HID_, HID_, HID_);
}

// Round 2
// 1172.501 us; speedup vs baseline: 1.1539x; 1.1476x over previous
//
#include <hip/hip_runtime.h>
#include <hip/hip_bf16.h>
#include <hip/hip_fp16.h>
#include <stdint.h>

typedef __hip_bfloat16 bf16;
using bf16x8 = __attribute__((ext_vector_type(8))) short;     // 8 bf16
using half8  = __attribute__((ext_vector_type(8))) _Float16;  // 8 fp16
using f32x4  = __attribute__((ext_vector_type(4))) float;

#define S_LEN   4096
#define HID_    2048
#define NH_     16
#define D_      128
#define C_      1024
#define SCALE_  0.08838834764831845f   // 1/sqrt(128)
#define DESC_   (1.0 / 1048576.0)      // 2^-20 (undo ×1024 on both operands)

__device__ __forceinline__ float bflo(uint32_t u) {
  uint32_t x = (u & 0xffffu) << 16; float f; __builtin_memcpy(&f, &x, 4); return f;
}
__device__ __forceinline__ float bfhi(uint32_t u) {
  uint32_t x = u & 0xffff0000u; float f; __builtin_memcpy(&f, &x, 4); return f;
}
__device__ __forceinline__ void storeC(float* p, float v) { *p = v; }
__device__ __forceinline__ void storeC(bf16* p, float v)  { *p = __float2bfloat16(v); }
__device__ __forceinline__ void split2(float x, _Float16& h, _Float16& l) {
  h = (_Float16)x; l = (_Float16)(x - (float)h);
}
__device__ __forceinline__ short bf2s(bf16 b) { short s; __builtin_memcpy(&s, &b, 2); return s; }

// ---------------- fp32 -> bf16 convert (hidden) ----------------
__global__ __launch_bounds__(256) void cvt_k(const float* __restrict__ src, bf16* __restrict__ dst) {
  int i = (blockIdx.x * 256 + threadIdx.x) * 4;
  float4 v = *(const float4*)(src + i);
  bf16 o[4] = {__float2bfloat16(v.x), __float2bfloat16(v.y),
               __float2bfloat16(v.z), __float2bfloat16(v.w)};
  *(uint2*)(dst + i) = *(uint2*)o;
}

// ---------------- fp32 -> fp16 hi/lo split (x1024), contiguous ----------------
__global__ __launch_bounds__(256) void split_q_k(const float* __restrict__ src,
                                                 _Float16* __restrict__ oh, _Float16* __restrict__ ol) {
  int i = (blockIdx.x * 256 + threadIdx.x) * 4;
  float4 v = *(const float4*)(src + i);
  float xs[4] = {v.x, v.y, v.z, v.w};
  _Float16 hh[4], ll[4];
#pragma unroll
  for (int e = 0; e < 4; ++e) split2(xs[e] * 1024.0f, hh[e], ll[e]);
  *(uint2*)(oh + i) = *(uint2*)hh;
  *(uint2*)(ol + i) = *(uint2*)ll;
}

// ---------------- ck split: ckvF rows (stride 256, first 128 cols) -> [c][k] fp16 hi/lo ----------------
__global__ __launch_bounds__(256) void split_ck_k(const float* __restrict__ ckvF,
                                                  _Float16* __restrict__ oh, _Float16* __restrict__ ol) {
  int idx = blockIdx.x * 256 + threadIdx.x;     // c*128 + k, total 131072
  int c = idx >> 7, k = idx & 127;
  float x = ckvF[(size_t)c * 256 + k] * 1024.0f;
  _Float16 h, l; split2(x, h, l);
  oh[idx] = h; ol[idx] = l;
}

// ---------------- transpose: fp32 (R x N) -> bf16 (N x R) ----------------
__global__ __launch_bounds__(256) void transpose_k(const float* __restrict__ src,
                                                   bf16* __restrict__ dst, int R, int N) {
  __shared__ float tile[64][65];
  const int c0 = blockIdx.x * 64, r0 = blockIdx.y * 64;
  const int t = threadIdx.x, cc = t & 63, rb = t >> 6;
#pragma unroll
  for (int i = 0; i < 16; ++i) {
    int r = rb + i * 4;
    tile[r][cc] = src[(size_t)(r0 + r) * N + c0 + cc];
  }
  __syncthreads();
#pragma unroll
  for (int i = 0; i < 16; ++i) {
    int r = rb + i * 4;
    dst[(size_t)(c0 + r) * R + r0 + cc] = __float2bfloat16(tile[cc][r]);
  }
}

// ---------------- transpose: fp32 (R x N) -> fp32 (N x R), prescaled x1024 ----------------
__global__ __launch_bounds__(256) void trans_f32s(const float* __restrict__ src,
                                                  float* __restrict__ dst, int R, int N) {
  __shared__ float tile[64][65];
  const int c0 = blockIdx.x * 64, r0 = blockIdx.y * 64;
  const int t = threadIdx.x, cc = t & 63, rb = t >> 6;
#pragma unroll
  for (int i = 0; i < 16; ++i) {
    int r = rb + i * 4;
    tile[r][cc] = src[(size_t)(r0 + r) * N + c0 + cc];
  }
  __syncthreads();
#pragma unroll
  for (int i = 0; i < 16; ++i) {
    int r = rb + i * 4;
    dst[(size_t)(c0 + r) * R + r0 + cc] = tile[cc][r] * 1024.0f;
  }
}

// ---------------- transpose lv half of lklv (bf16 [4096][2048-slice]) -> VT [2048][4096] ----------------
__global__ __launch_bounds__(256) void trans_v_k(const bf16* __restrict__ lklv, bf16* __restrict__ VT) {
  __shared__ ushort tile[64][65];
  const int s0 = blockIdx.x * 64, c0 = blockIdx.y * 64;  // c indexes h*128+d in [0,2048)
  const int t = threadIdx.x, cc = t & 63, rb = t >> 6;
  const ushort* src = (const ushort*)lklv;
#pragma unroll
  for (int i = 0; i < 16; ++i) {
    int r = rb + i * 4;
    tile[r][cc] = src[(size_t)(s0 + r) * 4096 + 2048 + c0 + cc];
  }
  __syncthreads();
  ushort* dst = (ushort*)VT;
#pragma unroll
  for (int i = 0; i < 16; ++i) {
    int r = rb + i * 4;
    dst[(size_t)(c0 + r) * 4096 + s0 + cc] = tile[cc][r];
  }
}

// ---------------- bias concat ----------------
__global__ void build_bias(const float* bq, const float* blk, const float* blv,
                           const float* bk, const float* bv, const float* bo,
                           float* bQ, float* bLKLV, float* bKV, float* bO) {
  int i = blockIdx.x * 256 + threadIdx.x;
  if (i < 2048)       bQ[i] = bq[i];
  else if (i < 6144)  { int j = i - 2048; bLKLV[j] = (j < 2048) ? blk[j] : blv[j - 2048]; }
  else if (i < 6400)  { int j = i - 6144; bKV[j] = (j < 128) ? bk[j] : bv[j - 128]; }
  else if (i < 8448)  bO[i - 6400] = bo[i - 6400];
}

// ---------------- plain m97-style bf16 GEMM ----------------
template <typename OutT>
__global__ __launch_bounds__(256) void gemm_bt(const bf16* __restrict__ A, const bf16* __restrict__ BT,
                                               const float* __restrict__ bias, OutT* __restrict__ Cmat,
                                               int M, int N, int K, int lda) {
  __shared__ bf16 As[128 * 32];
  __shared__ bf16 Bs[128 * 32];
  const int t = threadIdx.x;
  const int wave = t >> 6, lane = t & 63;
  const int wr = wave >> 1, wc = wave & 1;
  const int quad = lane >> 4, l15 = lane & 15;
  const int bx = blockIdx.x * 128, by = blockIdx.y * 128;
  const int srow = t >> 2, scol = (t & 3) * 8;
  f32x4 acc[4][4] = {};
  const bf16* a0 = A + (size_t)(by + srow) * lda + scol;
  const bf16* a1 = A + (size_t)(by + 64 + srow) * lda + scol;
  const bf16* b0 = BT + (size_t)(bx + srow) * K + scol;
  const bf16* b1 = BT + (size_t)(bx + 64 + srow) * K + scol;
  for (int k0 = 0; k0 < K; k0 += 32) {
    __builtin_amdgcn_global_load_lds((const __attribute__((address_space(1))) void*)(a0 + k0),
                                     (__attribute__((address_space(3))) void*)(As + t * 8), 16, 0, 0);
    __builtin_amdgcn_global_load_lds((const __attribute__((address_space(1))) void*)(a1 + k0),
                                     (__attribute__((address_space(3))) void*)(As + 2048 + t * 8), 16, 0, 0);
    __builtin_amdgcn_global_load_lds((const __attribute__((address_space(1))) void*)(b0 + k0),
                                     (__attribute__((address_space(3))) void*)(Bs + t * 8), 16, 0, 0);
    __builtin_amdgcn_global_load_lds((const __attribute__((address_space(1))) void*)(b1 + k0),
                                     (__attribute__((address_space(3))) void*)(Bs + 2048 + t * 8), 16, 0, 0);
    __syncthreads();
    bf16x8 aF[4], bF[4];
#pragma unroll
    for (int i = 0; i < 4; ++i)
      aF[i] = *(const bf16x8*)(As + (wr * 64 + i * 16 + l15) * 32 + quad * 8);
#pragma unroll
    for (int j = 0; j < 4; ++j)
      bF[j] = *(const bf16x8*)(Bs + (wc * 64 + j * 16 + l15) * 32 + quad * 8);
#pragma unroll
    for (int i = 0; i < 4; ++i)
#pragma unroll
      for (int j = 0; j < 4; ++j)
        acc[i][j] = __builtin_amdgcn_mfma_f32_16x16x32_bf16(aF[i], bF[j], acc[i][j], 0, 0, 0);
    __syncthreads();
  }
#pragma unroll
  for (int i = 0; i < 4; ++i)
#pragma unroll
    for (int j = 0; j < 4; ++j)
#pragma unroll
      for (int r = 0; r < 4; ++r) {
        int row = by + wr * 64 + i * 16 + quad * 4 + r;
        int col = bx + wc * 64 + j * 16 + l15;
        storeC(&Cmat[(size_t)row * N + col], acc[i][j][r] + bias[col]);
      }
}

// ---------------- precise GEMM: fp16 2-way split, 4 MFMA terms, fp64 per-kstep accum ----------------
__global__ __launch_bounds__(256) void gemm_prec4(const float* __restrict__ A, const float* __restrict__ BT,
                                                  const float* __restrict__ bias, float* __restrict__ Cmat,
                                                  int M, int N, int K, int lda) {
  __shared__ _Float16 Ah[128 * 32], Al[128 * 32], Bh[128 * 32], Bl[128 * 32];
  const int t = threadIdx.x;
  const int wave = t >> 6, lane = t & 63;
  const int wr = wave >> 1, wc = wave & 1;
  const int quad = lane >> 4, l15 = lane & 15;
  const int bx = blockIdx.x * 128, by = blockIdx.y * 128;
  double acc[4][4][4] = {};
  for (int k0 = 0; k0 < K; k0 += 32) {
#pragma unroll
    for (int it = 0; it < 4; ++it) {
      int sl = t + it * 256;
      int isB = sl >> 9, s2 = sl & 511, r = s2 >> 2, g = s2 & 3;
      const float* src = isB ? (BT + (size_t)(bx + r) * K + k0 + g * 8)
                             : (A  + (size_t)(by + r) * lda + k0 + g * 8);
      float4 u = ((const float4*)src)[0];
      float4 v = ((const float4*)src)[1];
      float xs[8] = {u.x, u.y, u.z, u.w, v.x, v.y, v.z, v.w};
      half8 hh, ll;
#pragma unroll
      for (int e = 0; e < 8; ++e) {
        float x = isB ? xs[e] : xs[e] * 1024.0f;
        _Float16 h, l; split2(x, h, l);
        hh[e] = h; ll[e] = l;
      }
      _Float16* dh = (isB ? Bh : Ah) + r * 32 + g * 8;
      _Float16* dl = (isB ? Bl : Al) + r * 32 + g * 8;
      *(half8*)dh = hh;
      *(half8*)dl = ll;
    }
    __syncthreads();
    half8 aFh[4], aFl[4], bFh[4], bFl[4];
#pragma unroll
    for (int i = 0; i < 4; ++i) {
      int ro = (wr * 64 + i * 16 + l15) * 32 + quad * 8;
      aFh[i] = *(const half8*)(Ah + ro);
      aFl[i] = *(const half8*)(Al + ro);
    }
#pragma unroll
    for (int j = 0; j < 4; ++j) {
      int ro = (wc * 64 + j * 16 + l15) * 32 + quad * 8;
      bFh[j] = *(const half8*)(Bh + ro);
      bFl[j] = *(const half8*)(Bl + ro);
    }
#pragma unroll
    for (int i = 0; i < 4; ++i)
#pragma unroll
      for (int j = 0; j < 4; ++j) {
        f32x4 tt = {0.f, 0.f, 0.f, 0.f};
        tt = __builtin_amdgcn_mfma_f32_16x16x32_f16(aFl[i], bFl[j], tt, 0, 0, 0);
        tt = __builtin_amdgcn_mfma_f32_16x16x32_f16(aFl[i], bFh[j], tt, 0, 0, 0);
        tt = __builtin_amdgcn_mfma_f32_16x16x32_f16(aFh[i], bFl[j], tt, 0, 0, 0);
        tt = __builtin_amdgcn_mfma_f32_16x16x32_f16(aFh[i], bFh[j], tt, 0, 0, 0);
#pragma unroll
        for (int r = 0; r < 4; ++r) acc[i][j][r] += (double)tt[r];
      }
    __syncthreads();
  }
#pragma unroll
  for (int i = 0; i < 4; ++i)
#pragma unroll
    for (int j = 0; j < 4; ++j)
#pragma unroll
      for (int r = 0; r < 4; ++r) {
        int row = by + wr * 64 + i * 16 + quad * 4 + r;
        int col = bx + wc * 64 + j * 16 + l15;
        Cmat[(size_t)row * N + col] = (float)(acc[i][j][r] * DESC_ + (double)bias[col]);
      }
}

// ---------------- fp64 rmsnorm + fp32-faithful rope, fp32 buffer in place ----------------
__global__ __launch_bounds__(256) void normrope64(float* __restrict__ base, const float* __restrict__ w,
                                                  int nRows, int hPerS, int sStride,
                                                  int posMul, int posAdd) {
  int row = blockIdx.x * 4 + (threadIdx.x >> 6);
  int lane = threadIdx.x & 63;
  if (row >= nRows) return;
  int s = row / hPerS, h = row - s * hPerS;
  float* p = base + (size_t)s * sStride + h * 128;
  double x0 = (double)p[lane];
  double x1 = (double)p[lane + 64];
  double ss = x0 * x0 + x1 * x1;
#pragma unroll
  for (int m = 32; m; m >>= 1) ss += __shfl_xor(ss, m, 64);
  double rstd = 1.0 / sqrt(ss * (1.0 / 128.0) + 1e-6);
  double n0 = x0 * rstd * (double)w[lane];
  double n1 = x1 * rstd * (double)w[lane + 64];
  double other = __shfl_xor(n0, 32, 64);
  int fi = lane & 31;
  float invf = 1.0f / (float)pow(10000.0, (double)fi * (1.0 / 32.0));
  float angf = (float)(s * posMul + posAdd) * invf;
  double ang = (double)angf;
  double cs = cos(ang), sn = sin(ang);
  double r0 = (lane < 32) ? (n0 * cs - other * sn) : (other * sn + n0 * cs);
  p[lane] = (float)r0;
  p[lane + 64] = (float)n1;
}

// ---------------- bf16 rmsnorm+rope (smooth lk path) ----------------
__global__ __launch_bounds__(256) void normrope_bf(bf16* __restrict__ base, const float* __restrict__ w,
                                                   int nRows, int hPerS, int sStride) {
  int row = blockIdx.x * 4 + (threadIdx.x >> 6);
  int lane = threadIdx.x & 63;
  if (row >= nRows) return;
  int s = row / hPerS, h = row - s * hPerS;
  bf16* p = base + (size_t)s * sStride + h * 128;
  float x0 = __bfloat162float(p[lane]);
  float x1 = __bfloat162float(p[lane + 64]);
  float ss = x0 * x0 + x1 * x1;
#pragma unroll
  for (int m = 32; m; m >>= 1) ss += __shfl_xor(ss, m, 64);
  float rstd = rsqrtf(ss * 0.0078125f + 1e-6f);
  float n0 = x0 * rstd * w[lane];
  float n1 = x1 * rstd * w[lane + 64];
  float other = __shfl_xor(n0, 32, 64);
  int fi = lane & 31;
  float invf = 1.0f / (float)pow(10000.0, (double)fi * (1.0 / 32.0));
  float ang = (float)s * invf;
  float cs = cosf(ang), sn = sinf(ang);
  float r0 = (lane < 32) ? (n0 * cs - other * sn) : (other * sn + n0 * cs);
  p[lane] = __float2bfloat16(r0);
  p[lane + 64] = __float2bfloat16(n1);
}

// ---------------- compress logits (fp64) ----------------
__global__ __launch_bounds__(256) void wlog_k(const float* __restrict__ hidden, const float* __restrict__ wcmp,
                                              const float* __restrict__ bcmp, float* __restrict__ wlog) {
  int s = blockIdx.x * 4 + (threadIdx.x >> 6);
  int lane = threadIdx.x & 63;
  const float* hp = hidden + (size_t)s * HID_;
  double acc = 0.0;
  for (int i = lane; i < HID_; i += 64)
    acc += (double)hp[i] * (double)wcmp[i];
#pragma unroll
  for (int m = 32; m; m >>= 1) acc += __shfl_xor(acc, m, 64);
  if (lane == 0) wlog[s] = (float)(acc + (double)bcmp[0]);
}

__global__ void wsm_k(const float* __restrict__ wlog, float* __restrict__ wsm) {
  int c = blockIdx.x * 256 + threadIdx.x;
  if (c >= C_) return;
  double v[4], m = -1e300;
#pragma unroll
  for (int r = 0; r < 4; ++r) { v[r] = (double)wlog[4 * c + r]; if (v[r] > m) m = v[r]; }
  double sum = 0.0;
#pragma unroll
  for (int r = 0; r < 4; ++r) { v[r] = exp(v[r] - m); sum += v[r]; }
#pragma unroll
  for (int r = 0; r < 4; ++r) wsm[4 * c + r] = (float)(v[r] / sum);
}

__global__ __launch_bounds__(256) void entries_k(const float* __restrict__ hidden, const float* __restrict__ wsm,
                                                 float* __restrict__ entriesF) {
  int idx = blockIdx.x * 256 + threadIdx.x;     // c*2048 + hcol
  int c = idx >> 11, hcol = idx & 2047;
  double e = 0.0;
#pragma unroll
  for (int r = 0; r < 4; ++r)
    e += (double)wsm[4 * c + r] * (double)hidden[(size_t)(4 * c + r) * HID_ + hcol];
  entriesF[idx] = (float)e;
}

// ---------------- sparse v8: 8 queries x 2 heads per block, 16 waves ----------------
__global__ __launch_bounds__(1024, 8) void sparse_v8(const _Float16* __restrict__ qh, const _Float16* __restrict__ ql,
                                                     const _Float16* __restrict__ ckh, const _Float16* __restrict__ ckl,
                                                     const float* __restrict__ ckvF, bf16* __restrict__ sp) {
  __shared__ float sc[16 * 1024];               // 64 KB -> 2 blocks/CU (32 waves)
  const int by = blockIdx.y;                    // head pair: heads 2*by, 2*by+1
  const int s0 = blockIdx.x * 8;
  const int t = threadIdx.x, w = t >> 6, lane = t & 63;
  const int quad = lane >> 4, l15 = lane & 15;
  // A row m: query s0+(m&7), head 2*by+(m>>3)
  const int sA = s0 + (l15 & 7);
  const int hA = 2 * by + (l15 >> 3);
  half8 aFh[4], aFl[4];
  {
    const _Float16* qbh = qh + (size_t)sA * HID_ + hA * 128 + quad * 8;
    const _Float16* qbl = ql + (size_t)sA * HID_ + hA * 128 + quad * 8;
#pragma unroll
    for (int kk = 0; kk < 4; ++kk) {
      aFh[kk] = *(const half8*)(qbh + kk * 32);
      aFl[kk] = *(const half8*)(qbl + kk * 32);
    }
  }
  const int nvmax  = (s0 >> 2) + 2;             // max causally valid blocks for s in [s0,s0+8)
  const int ntiles = (nvmax + 15) >> 4;
  const double esc = (double)SCALE_ * DESC_;
  for (int ct = w; ct < ntiles; ct += 16) {
    const int c0 = ct * 16;
    const _Float16* kbh = ckh + (size_t)(c0 + l15) * 128 + quad * 8;
    const _Float16* kbl = ckl + (size_t)(c0 + l15) * 128 + quad * 8;
    double a64[4] = {0.0, 0.0, 0.0, 0.0};
#pragma unroll
    for (int kk = 0; kk < 4; ++kk) {
      half8 bh = *(const half8*)(kbh + kk * 32);
      half8 bl = *(const half8*)(kbl + kk * 32);
      f32x4 tt = {0.f, 0.f, 0.f, 0.f};
      tt = __builtin_amdgcn_mfma_f32_16x16x32_f16(aFl[kk], bl, tt, 0, 0, 0);
      tt = __builtin_amdgcn_mfma_f32_16x16x32_f16(aFl[kk], bh, tt, 0, 0, 0);
      tt = __builtin_amdgcn_mfma_f32_16x16x32_f16(aFh[kk], bl, tt, 0, 0, 0);
      tt = __builtin_amdgcn_mfma_f32_16x16x32_f16(aFh[kk], bh, tt, 0, 0, 0);
#pragma unroll
      for (int r = 0; r < 4; ++r) a64[r] += (double)tt[r];
    }
#pragma unroll
    for (int r = 0; r < 4; ++r)                 // all 16 C rows are real (q, head) pairs
      sc[(quad * 4 + r) * 1024 + c0 + l15] = (float)(a64[r] * esc);
  }
  __syncthreads();
  // ---- phase 2: wave w -> chain (head parity p = w>>3, query s0 + (w&7)) ----
  const int p = w >> 3, wq = w & 7;
  const int s = s0 + wq;
  const int nv = (s >= 3) ? (((s - 3) >> 2) + 1) : 0;
  const int jmax = (nv + 63) >> 6;              // wave-uniform valid j-tile count (0..16)
  const float* srow = sc + (p * 8 + wq) * 1024 + lane;
  // initial per-lane top-2 over valid candidates (strict > keeps lowest c on ties)
  float v1 = -1e38f, v2 = -1e38f; int i1 = 0x40000000, i2 = 0x40000000;
  for (int j = 0; j < jmax; ++j) {
    int c = j * 64 + lane;
    float v = (c < nv) ? srow[j * 64] : -1e38f;
    if (v > v1)      { v2 = v1; i2 = i1; v1 = v; i1 = c; }
    else if (v > v2) { v2 = v; i2 = c; }
  }
  uint32_t dead = 0u;
  bool need2 = false;                           // true: v2/i2 stale (consumed, not refilled)
  float bvs[8]; int bis[8];
#pragma unroll
  for (int it = 0; it < 8; ++it) {
    float bv = v1; int bi = i1;
#pragma unroll
    for (int mm = 32; mm; mm >>= 1) {
      float ov = __shfl_xor(bv, mm, 64);
      int   oi = __shfl_xor(bi, mm, 64);
      if (ov > bv || (ov == bv && oi < bi)) { bv = ov; bi = oi; }  // max value, lowest index
    }
    bvs[it] = bv; bis[it] = bi;
    if (bv > -1e29f && (bi & 63) == lane) {     // this lane owned the global winner
      dead |= 1u << (i1 >> 6);
      if (!need2) { v1 = v2; i1 = i2; need2 = true; }
      else {
        // second consecutive consumption: rescan alive candidates for a fresh top-2
        v1 = -1e38f; i1 = 0x40000000; v2 = -1e38f; i2 = 0x40000000;
        for (int j = 0; j < jmax; ++j) {
          if (!((dead >> j) & 1u)) {
            int c = j * 64 + lane;
            float v = (c < nv) ? srow[j * 64] : -1e38f;
            if (v > v1)      { v2 = v1; i2 = i1; v1 = v; i1 = c; }
            else if (v > v2) { v2 = v; i2 = c; }
          }
        }
        need2 = false;
      }
    }
  }
  // deferred gathers
  const float m = bvs[0];
  float esum = 0.f, cacc0 = 0.f, cacc1 = 0.f;
#pragma unroll
  for (int it = 0; it < 8; ++it) {
    if (bvs[it] > -1e29f) {
      float wgt = expf(bvs[it] - m);
      esum += wgt;
      const float* cvp = ckvF + (size_t)bis[it] * 256 + 128;
      cacc0 += wgt * cvp[lane];
      cacc1 += wgt * cvp[lane + 64];
    }
  }
  float inv = 1.0f / fmaxf(esum, 1e-9f);
  bf16* op = sp + (size_t)s * 2048 + (2 * by + p) * 128;
  op[lane] = __float2bfloat16(cacc0 * inv);
  op[lane + 64] = __float2bfloat16(cacc1 * inv);
}

// ---------------- local sliding-window via MFMA ----------------
// 2 waves/block, each wave owns 16 queries x 1 head, 144-key window (9 tiles).
// QK^T: A = Q split into bf16 hi+lo (2-term, ~17-bit mantissa), B = K native bf16
// straight from global (no conversion). Softmax in C-layout registers. P -> bf16
// hi/lo through wave-private LDS (stride 168: bank-distinct, 16B aligned) to reach
// A-fragment layout; V read in B-fragment layout from pre-transposed VT.
// No __syncthreads anywhere (wave-private LDS regions).
__global__ __launch_bounds__(128) void local_mfma(const float* __restrict__ qf,
                                                  const bf16* __restrict__ lklv,
                                                  const bf16* __restrict__ VT,
                                                  const bf16* __restrict__ sp,
                                                  bf16* __restrict__ merged) {
  constexpr int PADP = 168;                     // 336B row stride: all-16-rows bank-distinct-ish (2-way max)
  __shared__ bf16 PhS[2][16 * PADP];
  __shared__ bf16 PlS[2][16 * PADP];
  const int h = blockIdx.y;
  const int t = threadIdx.x, w = t >> 6, lane = t & 63;
  const int quad = lane >> 4, l15 = lane & 15;
  const int sw = blockIdx.x * 32 + w * 16;      // first query of this wave
  const int kbase = sw - 128;                   // first key of the 144-wide window (may be <0)
  const int ridx = quad * 4;                    // C-layout row base (query offset)

  // ---- Q fragments: bf16 2-term split (A-layout: row=l15, k=quad*8+e+32kk) ----
  bf16x8 qH[4], qL[4];
  {
    const float* qp = qf + (size_t)(sw + l15) * HID_ + h * 128 + quad * 8;
#pragma unroll
    for (int kk = 0; kk < 4; ++kk) {
      float4 u = *(const float4*)(qp + kk * 32);
      float4 v = *(const float4*)(qp + kk * 32 + 4);
      float xs[8] = {u.x, u.y, u.z, u.w, v.x, v.y, v.z, v.w};
      bf16x8 hh, ll;
#pragma unroll
      for (int e = 0; e < 8; ++e) {
        bf16 bh = __float2bfloat16(xs[e]);
        float fh = __bfloat162float(bh);
        bf16 bl = __float2bfloat16(xs[e] - fh);
        hh[e] = bf2s(bh); ll[e] = bf2s(bl);
      }
      qH[kk] = hh; qL[kk] = ll;
    }
  }

  // ---- QK^T: 9 key tiles, K read direct from lklv (B-layout: col=l15 key, k=quad*8+e) ----
  float sc[9][4];
#pragma unroll
  for (int ct = 0; ct < 9; ++ct) {
    int key0 = kbase + ct * 16 + l15;
    const bf16* kp = lklv + (size_t)(key0 < 0 ? 0 : key0) * 4096 + h * 128 + quad * 8;
    f32x4 acc = {0.f, 0.f, 0.f, 0.f};
#pragma unroll
    for (int kk = 0; kk < 4; ++kk) {
      bf16x8 kb = *(const bf16x8*)(kp + kk * 32);
      acc = __builtin_amdgcn_mfma_f32_16x16x32_bf16(qL[kk], kb, acc, 0, 0, 0);
      acc = __builtin_amdgcn_mfma_f32_16x16x32_bf16(qH[kk], kb, acc, 0, 0, 0);
    }
#pragma unroll
    for (int r = 0; r < 4; ++r) sc[ct][r] = acc[r] * SCALE_;
  }

  // ---- mask + row max (rows live in this quad; reduce over l15 via xor 1,2,4,8) ----
  float mrow[4] = {-1e30f, -1e30f, -1e30f, -1e30f};
#pragma unroll
  for (int ct = 0; ct < 9; ++ct) {
    int cidx = ct * 16 + l15;
#pragma unroll
    for (int r = 0; r < 4; ++r) {
      bool valid = (cidx >= ridx + r) && (cidx <= ridx + r + 128) && (kbase + cidx >= 0);
      float v = valid ? sc[ct][r] : -1e30f;
      sc[ct][r] = v;
      mrow[r] = fmaxf(mrow[r], v);
    }
  }
#pragma unroll
  for (int mm = 1; mm <= 8; mm <<= 1)
#pragma unroll
    for (int r = 0; r < 4; ++r) mrow[r] = fmaxf(mrow[r], __shfl_xor(mrow[r], mm, 64));

  // ---- exp, row sum, P -> LDS as bf16 hi/lo (zero-pad cols 144..159 for the 5th k-step) ----
  bf16* phb = &PhS[w][0];
  bf16* plb = &PlS[w][0];
  for (int z = lane; z < 256; z += 64) {
    int zr = z >> 4, zc = z & 15;
    phb[zr * PADP + 144 + zc] = __float2bfloat16(0.f);
    plb[zr * PADP + 144 + zc] = __float2bfloat16(0.f);
  }
  float lsum[4] = {0.f, 0.f, 0.f, 0.f};
#pragma unroll
  for (int ct = 0; ct < 9; ++ct) {
    int cidx = ct * 16 + l15;
#pragma unroll
    for (int r = 0; r < 4; ++r) {
      float e = (sc[ct][r] > -1e29f) ? expf(sc[ct][r] - mrow[r]) : 0.f;
      lsum[r] += e;
      bf16 bh = __float2bfloat16(e);
      float fh = __bfloat162float(bh);
      bf16 bl = __float2bfloat16(e - fh);
      phb[(ridx + r) * PADP + cidx] = bh;
      plb[(ridx + r) * PADP + cidx] = bl;
    }
  }
#pragma unroll
  for (int mm = 1; mm <= 8; mm <<= 1)
#pragma unroll
    for (int r = 0; r < 4; ++r) lsum[r] += __shfl_xor(lsum[r], mm, 64);
  float inv[4];
#pragma unroll
  for (int r = 0; r < 4; ++r) inv[r] = 1.0f / lsum[r];

  // ---- hoist P fragments (A-layout: row=l15, k=quad*8+e+32kk), reused across all 8 d-tiles ----
  bf16x8 pH[5], pL[5];
#pragma unroll
  for (int kk = 0; kk < 5; ++kk) {
    pH[kk] = *(const bf16x8*)(phb + l15 * PADP + kk * 32 + quad * 8);
    pL[kk] = *(const bf16x8*)(plb + l15 * PADP + kk * 32 + quad * 8);
  }

  // ---- PV: V in B-layout from VT (col=l15 -> d, k=key), accumulate, merge with sp ----
#pragma unroll
  for (int dt = 0; dt < 8; ++dt) {
    const bf16* vrow = VT + (size_t)(h * 128 + dt * 16 + l15) * 4096;
    f32x4 acc = {0.f, 0.f, 0.f, 0.f};
#pragma unroll
    for (int kk = 0; kk < 5; ++kk) {
      int ko = kbase + kk * 32 + quad * 8;
      ko = ko < 0 ? 0 : (ko > 4088 ? 4088 : ko);   // clamped lanes multiply zero P
      bf16x8 vb = *(const bf16x8*)(vrow + ko);
      acc = __builtin_amdgcn_mfma_f32_16x16x32_bf16(pL[kk], vb, acc, 0, 0, 0);
      acc = __builtin_amdgcn_mfma_f32_16x16x32_bf16(pH[kk], vb, acc, 0, 0, 0);
    }
#pragma unroll
    for (int r = 0; r < 4; ++r) {
      int srow = sw + ridx + r;
      size_t off = (size_t)srow * 2048 + h * 128 + dt * 16 + l15;
      float spv = __bfloat162float(sp[off]);
      merged[off] = __float2bfloat16((acc[r] * inv[r] + spv) * 0.5f);
    }
  }
}

// ---------------- host orchestration ----------------
extern "C" void kernel_launch(void* const* d_in, const int* in_sizes, int n_in,
                              void* d_out, int out_size, void* d_ws, size_t ws_size,
                              hipStream_t stream) {
  (void)in_sizes; (void)n_in; (void)out_size; (void)ws_size;
  const float* hidden = (const float*)d_in[0];
  const float* Wq   = (const float*)d_in[1];
  const float* bq   = (const float*)d_in[2];
  const float* Wcmp = (const float*)d_in[3];
  const float* bcmp = (const float*)d_in[4];
  const float* Wk   = (const float*)d_in[5];
  const float* bk   = (const float*)d_in[6];
  const float* Wv   = (const float*)d_in[7];
  const float* bv   = (const float*)d_in[8];
  const float* Wlk  = (const float*)d_in[9];
  const float* blk  = (const float*)d_in[10];
  const float* Wlv  = (const float*)d_in[11];
  const float* blv  = (const float*)d_in[12];
  const float* qn_w = (const float*)d_in[13];
  const float* kn_w = (const float*)d_in[14];
  const float* Wo   = (const float*)d_in[15];
  const float* bo   = (const float*)d_in[16];
  float* out = (float*)d_out;

  // workspace (~155 MB). Overlays: qh over WqTs (dead after q gemm), merged over hbf,
  // sp over bt_lklv (both dead after lklv gemm), VT over qh (dead after sparse_v8).
  char* ws = (char*)d_ws;
  float*    qf       = (float*)   (ws);                  // 33,554,432
  bf16*     lklv     = (bf16*)    (ws + 33554432);       // 33,554,432
  float*    WqTs     = (float*)   (ws + 67108864);       // 16,777,216 (x1024)
  _Float16* qh       = (_Float16*)(ws + 67108864);       // overlay of WqTs
  bf16*     VT       = (bf16*)    (ws + 67108864);       // overlay of qh: lv^T [2048][4096]
  bf16*     hbf      = (bf16*)    (ws + 83886080);       // 16,777,216
  bf16*     merged   = (bf16*)    (ws + 83886080);       // overlay of hbf
  bf16*     bt_lklv  = (bf16*)    (ws + 100663296);      // 16,777,216
  bf16*     sp       = (bf16*)    (ws + 100663296);      // overlay of bt_lklv
  float*    WkvTs    = (float*)   (ws + 117440512);      //  2,097,152 (x1024)
  bf16*     WoT      = (bf16*)    (ws + 119537664);      //  8,388,608
  float*    entriesF = (float*)   (ws + 127926272);      //  8,388,608
  float*    ckvF     = (float*)   (ws + 136314880);      //  1,048,576
  _Float16* ckh      = (_Float16*)(ws + 137363456);      //    262,144
  _Float16* ckl      = (_Float16*)(ws + 137625600);      //    262,144
  float*    wlog     = (float*)   (ws + 137887744);      //     16,384
  float*    wsm      = (float*)   (ws + 137904128);      //     16,384
  float*    bQ       = (float*)   (ws + 137920512);      //      8,192
  float*    bLKLV    = (float*)   (ws + 137928704);      //     16,384
  float*    bKV      = (float*)   (ws + 137945088);      //      1,024
  float*    bO       = (float*)   (ws + 137946112);      //      8,192
  _Float16* ql       = (_Float16*)(ws + 137954304);      // 16,777,216  (end ~154.7 MB)

  cvt_k<<<dim3(8192), dim3(256), 0, stream>>>(hidden, hbf);

  trans_f32s<<<dim3(32, 32), dim3(256), 0, stream>>>(Wq, WqTs, HID_, HID_);
  trans_f32s<<<dim3(2, 32),  dim3(256), 0, stream>>>(Wk, WkvTs, HID_, 128);
  trans_f32s<<<dim3(2, 32),  dim3(256), 0, stream>>>(Wv, WkvTs + (size_t)128 * HID_, HID_, 128);
  transpose_k<<<dim3(32, 32), dim3(256), 0, stream>>>(Wlk, bt_lklv, HID_, HID_);
  transpose_k<<<dim3(32, 32), dim3(256), 0, stream>>>(Wlv, bt_lklv + (size_t)2048 * HID_, HID_, HID_);
  transpose_k<<<dim3(32, 32), dim3(256), 0, stream>>>(Wo, WoT, HID_, HID_);
  build_bias<<<dim3(33), dim3(256), 0, stream>>>(bq, blk, blv, bk, bv, bo, bQ, bLKLV, bKV, bO);

  wlog_k<<<dim3(1024), dim3(256), 0, stream>>>(hidden, Wcmp, bcmp, wlog);
  wsm_k<<<dim3(4), dim3(256), 0, stream>>>(wlog, wsm);
  entries_k<<<dim3(8192), dim3(256), 0, stream>>>(hidden, wsm, entriesF);

  // precise projections
  gemm_prec4<<<dim3(16, 32), dim3(256), 0, stream>>>(hidden,   WqTs,  bQ,  qf,   S_LEN, HID_, HID_, HID_);
  gemm_prec4<<<dim3(2, 8),   dim3(256), 0, stream>>>(entriesF, WkvTs, bKV, ckvF, C_,    256,  HID_, HID_);
  // smooth lk|lv projection (bf16)
  gemm_bt<bf16><<<dim3(32, 32), dim3(256), 0, stream>>>(hbf, bt_lklv, bLKLV, lklv, S_LEN, 4096, HID_, HID_);

  // norms + rope
  normrope64<<<dim3(16384), dim3(256), 0, stream>>>(qf,   qn_w, 65536, 16, HID_, 1, 0);
  normrope64<<<dim3(256),   dim3(256), 0, stream>>>(ckvF, kn_w, 1024,  1,  256,  4, 3);
  normrope_bf<<<dim3(16384), dim3(256), 0, stream>>>(lklv, kn_w, 65536, 16, 4096);

  // pre-split operands for sparse scores (after norms/rope; qh safely overlays dead WqTs)
  split_q_k<<<dim3(8192), dim3(256), 0, stream>>>(qf, qh, ql);
  split_ck_k<<<dim3(512), dim3(256), 0, stream>>>(ckvF, ckh, ckl);

  // sparse branch first (consumes qh), then transpose lv into VT (overlays qh)
  sparse_v8<<<dim3(512, 8), dim3(1024), 0, stream>>>(qh, ql, ckh, ckl, ckvF, sp);
  trans_v_k<<<dim3(64, 32), dim3(256), 0, stream>>>(lklv, VT);
  local_mfma<<<dim3(128, 16), dim3(128), 0, stream>>>(qf, lklv, VT, sp, merged);

  // output projection
  gemm_bt<float><<<dim3(16, 32), dim3(256), 0, stream>>>(merged, WoT, bO, out, S_LEN, HID_, HID_, HID_);
}

// Round 3
// 1164.822 us; speedup vs baseline: 1.1615x; 1.0066x over previous
//
#include <hip/hip_runtime.h>
#include <hip/hip_bf16.h>
#include <hip/hip_fp16.h>
#include <stdint.h>

typedef __hip_bfloat16 bf16;
using bf16x8 = __attribute__((ext_vector_type(8))) short;     // 8 bf16
using half8  = __attribute__((ext_vector_type(8))) _Float16;  // 8 fp16
using f32x4  = __attribute__((ext_vector_type(4))) float;

#define S_LEN   4096
#define HID_    2048
#define NH_     16
#define D_      128
#define C_      1024
#define SCALE_  0.08838834764831845f   // 1/sqrt(128)
#define DESC_   (1.0 / 1048576.0)      // 2^-20 (undo ×1024 on both operands)

__device__ __forceinline__ float bflo(uint32_t u) {
  uint32_t x = (u & 0xffffu) << 16; float f; __builtin_memcpy(&f, &x, 4); return f;
}
__device__ __forceinline__ float bfhi(uint32_t u) {
  uint32_t x = u & 0xffff0000u; float f; __builtin_memcpy(&f, &x, 4); return f;
}
__device__ __forceinline__ void storeC(float* p, float v) { *p = v; }
__device__ __forceinline__ void storeC(bf16* p, float v)  { *p = __float2bfloat16(v); }
__device__ __forceinline__ void split2(float x, _Float16& h, _Float16& l) {
  h = (_Float16)x; l = (_Float16)(x - (float)h);
}
__device__ __forceinline__ short bf2s(bf16 b) { short s; __builtin_memcpy(&s, &b, 2); return s; }

// ---------------- fp32 -> bf16 convert (hidden) ----------------
__global__ __launch_bounds__(256) void cvt_k(const float* __restrict__ src, bf16* __restrict__ dst) {
  int i = (blockIdx.x * 256 + threadIdx.x) * 4;
  float4 v = *(const float4*)(src + i);
  bf16 o[4] = {__float2bfloat16(v.x), __float2bfloat16(v.y),
               __float2bfloat16(v.z), __float2bfloat16(v.w)};
  *(uint2*)(dst + i) = *(uint2*)o;
}

// ---------------- fp32 -> fp16 hi/lo split (x1024), contiguous ----------------
__global__ __launch_bounds__(256) void split_q_k(const float* __restrict__ src,
                                                 _Float16* __restrict__ oh, _Float16* __restrict__ ol) {
  int i = (blockIdx.x * 256 + threadIdx.x) * 4;
  float4 v = *(const float4*)(src + i);
  float xs[4] = {v.x, v.y, v.z, v.w};
  _Float16 hh[4], ll[4];
#pragma unroll
  for (int e = 0; e < 4; ++e) split2(xs[e] * 1024.0f, hh[e], ll[e]);
  *(uint2*)(oh + i) = *(uint2*)hh;
  *(uint2*)(ol + i) = *(uint2*)ll;
}

// ---------------- ck split: ckvF rows (stride 256, first 128 cols) -> [c][k] fp16 hi/lo ----------------
__global__ __launch_bounds__(256) void split_ck_k(const float* __restrict__ ckvF,
                                                  _Float16* __restrict__ oh, _Float16* __restrict__ ol) {
  int idx = blockIdx.x * 256 + threadIdx.x;     // c*128 + k, total 131072
  int c = idx >> 7, k = idx & 127;
  float x = ckvF[(size_t)c * 256 + k] * 1024.0f;
  _Float16 h, l; split2(x, h, l);
  oh[idx] = h; ol[idx] = l;
}

// ---------------- transpose: fp32 (R x N) -> bf16 (N x R) ----------------
__global__ __launch_bounds__(256) void transpose_k(const float* __restrict__ src,
                                                   bf16* __restrict__ dst, int R, int N) {
  __shared__ float tile[64][65];
  const int c0 = blockIdx.x * 64, r0 = blockIdx.y * 64;
  const int t = threadIdx.x, cc = t & 63, rb = t >> 6;
#pragma unroll
  for (int i = 0; i < 16; ++i) {
    int r = rb + i * 4;
    tile[r][cc] = src[(size_t)(r0 + r) * N + c0 + cc];
  }
  __syncthreads();
#pragma unroll
  for (int i = 0; i < 16; ++i) {
    int r = rb + i * 4;
    dst[(size_t)(c0 + r) * R + r0 + cc] = __float2bfloat16(tile[cc][r]);
  }
}

// ---------------- transpose: fp32 (R x N) -> fp32 (N x R), prescaled x1024 ----------------
__global__ __launch_bounds__(256) void trans_f32s(const float* __restrict__ src,
                                                  float* __restrict__ dst, int R, int N) {
  __shared__ float tile[64][65];
  const int c0 = blockIdx.x * 64, r0 = blockIdx.y * 64;
  const int t = threadIdx.x, cc = t & 63, rb = t >> 6;
#pragma unroll
  for (int i = 0; i < 16; ++i) {
    int r = rb + i * 4;
    tile[r][cc] = src[(size_t)(r0 + r) * N + c0 + cc];
  }
  __syncthreads();
#pragma unroll
  for (int i = 0; i < 16; ++i) {
    int r = rb + i * 4;
    dst[(size_t)(c0 + r) * R + r0 + cc] = tile[cc][r] * 1024.0f;
  }
}

// ---------------- transpose lv half of lklv (bf16 [4096][2048-slice]) -> VT [2048][4096] ----------------
__global__ __launch_bounds__(256) void trans_v_k(const bf16* __restrict__ lklv, bf16* __restrict__ VT) {
  __shared__ ushort tile[64][65];
  const int s0 = blockIdx.x * 64, c0 = blockIdx.y * 64;  // c indexes h*128+d in [0,2048)
  const int t = threadIdx.x, cc = t & 63, rb = t >> 6;
  const ushort* src = (const ushort*)lklv;
#pragma unroll
  for (int i = 0; i < 16; ++i) {
    int r = rb + i * 4;
    tile[r][cc] = src[(size_t)(s0 + r) * 4096 + 2048 + c0 + cc];
  }
  __syncthreads();
  ushort* dst = (ushort*)VT;
#pragma unroll
  for (int i = 0; i < 16; ++i) {
    int r = rb + i * 4;
    dst[(size_t)(c0 + r) * 4096 + s0 + cc] = tile[cc][r];
  }
}

// ---------------- bias concat ----------------
__global__ void build_bias(const float* bq, const float* blk, const float* blv,
                           const float* bk, const float* bv, const float* bo,
                           float* bQ, float* bLKLV, float* bKV, float* bO) {
  int i = blockIdx.x * 256 + threadIdx.x;
  if (i < 2048)       bQ[i] = bq[i];
  else if (i < 6144)  { int j = i - 2048; bLKLV[j] = (j < 2048) ? blk[j] : blv[j - 2048]; }
  else if (i < 6400)  { int j = i - 6144; bKV[j] = (j < 128) ? bk[j] : bv[j - 128]; }
  else if (i < 8448)  bO[i - 6400] = bo[i - 6400];
}

// ---------------- plain m97-style bf16 GEMM ----------------
template <typename OutT>
__global__ __launch_bounds__(256) void gemm_bt(const bf16* __restrict__ A, const bf16* __restrict__ BT,
                                               const float* __restrict__ bias, OutT* __restrict__ Cmat,
                                               int M, int N, int K, int lda) {
  __shared__ bf16 As[128 * 32];
  __shared__ bf16 Bs[128 * 32];
  const int t = threadIdx.x;
  const int wave = t >> 6, lane = t & 63;
  const int wr = wave >> 1, wc = wave & 1;
  const int quad = lane >> 4, l15 = lane & 15;
  const int bx = blockIdx.x * 128, by = blockIdx.y * 128;
  const int srow = t >> 2, scol = (t & 3) * 8;
  f32x4 acc[4][4] = {};
  const bf16* a0 = A + (size_t)(by + srow) * lda + scol;
  const bf16* a1 = A + (size_t)(by + 64 + srow) * lda + scol;
  const bf16* b0 = BT + (size_t)(bx + srow) * K + scol;
  const bf16* b1 = BT + (size_t)(bx + 64 + srow) * K + scol;
  for (int k0 = 0; k0 < K; k0 += 32) {
    __builtin_amdgcn_global_load_lds((const __attribute__((address_space(1))) void*)(a0 + k0),
                                     (__attribute__((address_space(3))) void*)(As + t * 8), 16, 0, 0);
    __builtin_amdgcn_global_load_lds((const __attribute__((address_space(1))) void*)(a1 + k0),
                                     (__attribute__((address_space(3))) void*)(As + 2048 + t * 8), 16, 0, 0);
    __builtin_amdgcn_global_load_lds((const __attribute__((address_space(1))) void*)(b0 + k0),
                                     (__attribute__((address_space(3))) void*)(Bs + t * 8), 16, 0, 0);
    __builtin_amdgcn_global_load_lds((const __attribute__((address_space(1))) void*)(b1 + k0),
                                     (__attribute__((address_space(3))) void*)(Bs + 2048 + t * 8), 16, 0, 0);
    __syncthreads();
    bf16x8 aF[4], bF[4];
#pragma unroll
    for (int i = 0; i < 4; ++i)
      aF[i] = *(const bf16x8*)(As + (wr * 64 + i * 16 + l15) * 32 + quad * 8);
#pragma unroll
    for (int j = 0; j < 4; ++j)
      bF[j] = *(const bf16x8*)(Bs + (wc * 64 + j * 16 + l15) * 32 + quad * 8);
#pragma unroll
    for (int i = 0; i < 4; ++i)
#pragma unroll
      for (int j = 0; j < 4; ++j)
        acc[i][j] = __builtin_amdgcn_mfma_f32_16x16x32_bf16(aF[i], bF[j], acc[i][j], 0, 0, 0);
    __syncthreads();
  }
#pragma unroll
  for (int i = 0; i < 4; ++i)
#pragma unroll
    for (int j = 0; j < 4; ++j)
#pragma unroll
      for (int r = 0; r < 4; ++r) {
        int row = by + wr * 64 + i * 16 + quad * 4 + r;
        int col = bx + wc * 64 + j * 16 + l15;
        storeC(&Cmat[(size_t)row * N + col], acc[i][j][r] + bias[col]);
      }
}

// ---------------- precise GEMM: fp16 2-way split, 4 MFMA terms, fp64 per-kstep accum ----------------
__global__ __launch_bounds__(256) void gemm_prec4(const float* __restrict__ A, const float* __restrict__ BT,
                                                  const float* __restrict__ bias, float* __restrict__ Cmat,
                                                  int M, int N, int K, int lda) {
  __shared__ _Float16 Ah[128 * 32], Al[128 * 32], Bh[128 * 32], Bl[128 * 32];
  const int t = threadIdx.x;
  const int wave = t >> 6, lane = t & 63;
  const int wr = wave >> 1, wc = wave & 1;
  const int quad = lane >> 4, l15 = lane & 15;
  const int bx = blockIdx.x * 128, by = blockIdx.y * 128;
  double acc[4][4][4] = {};
  for (int k0 = 0; k0 < K; k0 += 32) {
#pragma unroll
    for (int it = 0; it < 4; ++it) {
      int sl = t + it * 256;
      int isB = sl >> 9, s2 = sl & 511, r = s2 >> 2, g = s2 & 3;
      const float* src = isB ? (BT + (size_t)(bx + r) * K + k0 + g * 8)
                             : (A  + (size_t)(by + r) * lda + k0 + g * 8);
      float4 u = ((const float4*)src)[0];
      float4 v = ((const float4*)src)[1];
      float xs[8] = {u.x, u.y, u.z, u.w, v.x, v.y, v.z, v.w};
      half8 hh, ll;
#pragma unroll
      for (int e = 0; e < 8; ++e) {
        float x = isB ? xs[e] : xs[e] * 1024.0f;
        _Float16 h, l; split2(x, h, l);
        hh[e] = h; ll[e] = l;
      }
      _Float16* dh = (isB ? Bh : Ah) + r * 32 + g * 8;
      _Float16* dl = (isB ? Bl : Al) + r * 32 + g * 8;
      *(half8*)dh = hh;
      *(half8*)dl = ll;
    }
    __syncthreads();
    half8 aFh[4], aFl[4], bFh[4], bFl[4];
#pragma unroll
    for (int i = 0; i < 4; ++i) {
      int ro = (wr * 64 + i * 16 + l15) * 32 + quad * 8;
      aFh[i] = *(const half8*)(Ah + ro);
      aFl[i] = *(const half8*)(Al + ro);
    }
#pragma unroll
    for (int j = 0; j < 4; ++j) {
      int ro = (wc * 64 + j * 16 + l15) * 32 + quad * 8;
      bFh[j] = *(const half8*)(Bh + ro);
      bFl[j] = *(const half8*)(Bl + ro);
    }
#pragma unroll
    for (int i = 0; i < 4; ++i)
#pragma unroll
      for (int j = 0; j < 4; ++j) {
        f32x4 tt = {0.f, 0.f, 0.f, 0.f};
        tt = __builtin_amdgcn_mfma_f32_16x16x32_f16(aFl[i], bFl[j], tt, 0, 0, 0);
        tt = __builtin_amdgcn_mfma_f32_16x16x32_f16(aFl[i], bFh[j], tt, 0, 0, 0);
        tt = __builtin_amdgcn_mfma_f32_16x16x32_f16(aFh[i], bFl[j], tt, 0, 0, 0);
        tt = __builtin_amdgcn_mfma_f32_16x16x32_f16(aFh[i], bFh[j], tt, 0, 0, 0);
#pragma unroll
        for (int r = 0; r < 4; ++r) acc[i][j][r] += (double)tt[r];
      }
    __syncthreads();
  }
#pragma unroll
  for (int i = 0; i < 4; ++i)
#pragma unroll
    for (int j = 0; j < 4; ++j)
#pragma unroll
      for (int r = 0; r < 4; ++r) {
        int row = by + wr * 64 + i * 16 + quad * 4 + r;
        int col = bx + wc * 64 + j * 16 + l15;
        Cmat[(size_t)row * N + col] = (float)(acc[i][j][r] * DESC_ + (double)bias[col]);
      }
}

// ---------------- fp64 rmsnorm + fp32-faithful rope, fp32 buffer in place ----------------
__global__ __launch_bounds__(256) void normrope64(float* __restrict__ base, const float* __restrict__ w,
                                                  int nRows, int hPerS, int sStride,
                                                  int posMul, int posAdd) {
  int row = blockIdx.x * 4 + (threadIdx.x >> 6);
  int lane = threadIdx.x & 63;
  if (row >= nRows) return;
  int s = row / hPerS, h = row - s * hPerS;
  float* p = base + (size_t)s * sStride + h * 128;
  double x0 = (double)p[lane];
  double x1 = (double)p[lane + 64];
  double ss = x0 * x0 + x1 * x1;
#pragma unroll
  for (int m = 32; m; m >>= 1) ss += __shfl_xor(ss, m, 64);
  double rstd = 1.0 / sqrt(ss * (1.0 / 128.0) + 1e-6);
  double n0 = x0 * rstd * (double)w[lane];
  double n1 = x1 * rstd * (double)w[lane + 64];
  double other = __shfl_xor(n0, 32, 64);
  int fi = lane & 31;
  float invf = 1.0f / (float)pow(10000.0, (double)fi * (1.0 / 32.0));
  float angf = (float)(s * posMul + posAdd) * invf;
  double ang = (double)angf;
  double cs = cos(ang), sn = sin(ang);
  double r0 = (lane < 32) ? (n0 * cs - other * sn) : (other * sn + n0 * cs);
  p[lane] = (float)r0;
  p[lane + 64] = (float)n1;
}

// ---------------- bf16 rmsnorm+rope (smooth lk path) ----------------
__global__ __launch_bounds__(256) void normrope_bf(bf16* __restrict__ base, const float* __restrict__ w,
                                                   int nRows, int hPerS, int sStride) {
  int row = blockIdx.x * 4 + (threadIdx.x >> 6);
  int lane = threadIdx.x & 63;
  if (row >= nRows) return;
  int s = row / hPerS, h = row - s * hPerS;
  bf16* p = base + (size_t)s * sStride + h * 128;
  float x0 = __bfloat162float(p[lane]);
  float x1 = __bfloat162float(p[lane + 64]);
  float ss = x0 * x0 + x1 * x1;
#pragma unroll
  for (int m = 32; m; m >>= 1) ss += __shfl_xor(ss, m, 64);
  float rstd = rsqrtf(ss * 0.0078125f + 1e-6f);
  float n0 = x0 * rstd * w[lane];
  float n1 = x1 * rstd * w[lane + 64];
  float other = __shfl_xor(n0, 32, 64);
  int fi = lane & 31;
  float invf = 1.0f / (float)pow(10000.0, (double)fi * (1.0 / 32.0));
  float ang = (float)s * invf;
  float cs = cosf(ang), sn = sinf(ang);
  float r0 = (lane < 32) ? (n0 * cs - other * sn) : (other * sn + n0 * cs);
  p[lane] = __float2bfloat16(r0);
  p[lane + 64] = __float2bfloat16(n1);
}

// ---------------- compress logits (fp64) ----------------
__global__ __launch_bounds__(256) void wlog_k(const float* __restrict__ hidden, const float* __restrict__ wcmp,
                                              const float* __restrict__ bcmp, float* __restrict__ wlog) {
  int s = blockIdx.x * 4 + (threadIdx.x >> 6);
  int lane = threadIdx.x & 63;
  const float* hp = hidden + (size_t)s * HID_;
  double acc = 0.0;
  for (int i = lane; i < HID_; i += 64)
    acc += (double)hp[i] * (double)wcmp[i];
#pragma unroll
  for (int m = 32; m; m >>= 1) acc += __shfl_xor(acc, m, 64);
  if (lane == 0) wlog[s] = (float)(acc + (double)bcmp[0]);
}

__global__ void wsm_k(const float* __restrict__ wlog, float* __restrict__ wsm) {
  int c = blockIdx.x * 256 + threadIdx.x;
  if (c >= C_) return;
  double v[4], m = -1e300;
#pragma unroll
  for (int r = 0; r < 4; ++r) { v[r] = (double)wlog[4 * c + r]; if (v[r] > m) m = v[r]; }
  double sum = 0.0;
#pragma unroll
  for (int r = 0; r < 4; ++r) { v[r] = exp(v[r] - m); sum += v[r]; }
#pragma unroll
  for (int r = 0; r < 4; ++r) wsm[4 * c + r] = (float)(v[r] / sum);
}

__global__ __launch_bounds__(256) void entries_k(const float* __restrict__ hidden, const float* __restrict__ wsm,
                                                 float* __restrict__ entriesF) {
  int idx = blockIdx.x * 256 + threadIdx.x;     // c*2048 + hcol
  int c = idx >> 11, hcol = idx & 2047;
  double e = 0.0;
#pragma unroll
  for (int r = 0; r < 4; ++r)
    e += (double)wsm[4 * c + r] * (double)hidden[(size_t)(4 * c + r) * HID_ + hcol];
  entriesF[idx] = (float)e;
}

// ---------------- sparse v9: phase 1 as v8 (16 waves); phase 2 on 16-lane groups ----------------
// Phase 2: 4 chains per wave (group = lane>>4), 4 waves total; waves 4..15 exit.
// Selection: per-lane top-4 cache over candidates c = j*64 + l15*4 + e (ds_read_b128),
// 4-stage xor butterfly (1,2,4,8) within the 16-lane group. Rebuild (rare) only when a
// lane's cache is exhausted (4 consumptions). Same semantics as before: max value,
// lowest index on ties, stable ascending scan.
__global__ __launch_bounds__(1024, 8) void sparse_v9(const _Float16* __restrict__ qh, const _Float16* __restrict__ ql,
                                                     const _Float16* __restrict__ ckh, const _Float16* __restrict__ ckl,
                                                     const float* __restrict__ ckvF, bf16* __restrict__ sp) {
  __shared__ float sc[16 * 1024];               // 64 KB -> 2 blocks/CU
  const int by = blockIdx.y;                    // head pair: heads 2*by, 2*by+1
  const int s0 = blockIdx.x * 8;
  const int t = threadIdx.x, w = t >> 6, lane = t & 63;
  const int quad = lane >> 4, l15 = lane & 15;
  const int nvmax  = (s0 >> 2) + 2;             // max causally valid blocks for s in [s0,s0+8)
  const int ntiles = (nvmax + 15) >> 4;
  const double esc = (double)SCALE_ * DESC_;

  // ---- phase 1: score tiles distributed over 16 waves (A rows = 16 (q,h) chains) ----
  if (w < ntiles) {
    const int sA = s0 + (l15 & 7);
    const int hA = 2 * by + (l15 >> 3);
    half8 aFh[4], aFl[4];
    {
      const _Float16* qbh = qh + (size_t)sA * HID_ + hA * 128 + quad * 8;
      const _Float16* qbl = ql + (size_t)sA * HID_ + hA * 128 + quad * 8;
#pragma unroll
      for (int kk = 0; kk < 4; ++kk) {
        aFh[kk] = *(const half8*)(qbh + kk * 32);
        aFl[kk] = *(const half8*)(qbl + kk * 32);
      }
    }
    for (int ct = w; ct < ntiles; ct += 16) {
      const int c0 = ct * 16;
      const _Float16* kbh = ckh + (size_t)(c0 + l15) * 128 + quad * 8;
      const _Float16* kbl = ckl + (size_t)(c0 + l15) * 128 + quad * 8;
      double a64[4] = {0.0, 0.0, 0.0, 0.0};
#pragma unroll
      for (int kk = 0; kk < 4; ++kk) {
        half8 bh = *(const half8*)(kbh + kk * 32);
        half8 bl = *(const half8*)(kbl + kk * 32);
        f32x4 tt = {0.f, 0.f, 0.f, 0.f};
        tt = __builtin_amdgcn_mfma_f32_16x16x32_f16(aFl[kk], bl, tt, 0, 0, 0);
        tt = __builtin_amdgcn_mfma_f32_16x16x32_f16(aFl[kk], bh, tt, 0, 0, 0);
        tt = __builtin_amdgcn_mfma_f32_16x16x32_f16(aFh[kk], bl, tt, 0, 0, 0);
        tt = __builtin_amdgcn_mfma_f32_16x16x32_f16(aFh[kk], bh, tt, 0, 0, 0);
#pragma unroll
        for (int r = 0; r < 4; ++r) a64[r] += (double)tt[r];
      }
#pragma unroll
      for (int r = 0; r < 4; ++r)
        sc[(quad * 4 + r) * 1024 + c0 + l15] = (float)(a64[r] * esc);
    }
  }
  __syncthreads();
  if (w >= 4) return;

  // ---- phase 2: chain q = w*4 + quad, handled by 16 lanes (l15) ----
  const int q = w * 4 + quad;                   // == row in sc
  const int p2 = q >> 3, wq = q & 7;
  const int s = s0 + wq;
  const int nv = (s >= 3) ? (((s - 3) >> 2) + 1) : 0;
  const float* srow = sc + q * 1024;
  const int jmaxB = (nvmax + 63) >> 6;          // block-uniform j-tile count (1..16)

  // per-lane top-4 cache (tv[0] best; stable: ascending c, strict >)
  float tv0 = -1e38f, tv1 = -1e38f, tv2 = -1e38f, tv3 = -1e38f;
  int   ti0 = 0x40000000, ti1 = 0x40000000, ti2 = 0x40000000, ti3 = 0x40000000;
  for (int j = 0; j < jmaxB; ++j) {
    int cb = j * 64 + l15 * 4;
    float4 vv = *(const float4*)(srow + cb);
    float xs[4] = {vv.x, vv.y, vv.z, vv.w};
#pragma unroll
    for (int e = 0; e < 4; ++e) {
      int c = cb + e;
      float v = (c < nv) ? xs[e] : -1e38f;
      if (v > tv3) {
        if (v > tv0)      { tv3=tv2;ti3=ti2; tv2=tv1;ti2=ti1; tv1=tv0;ti1=ti0; tv0=v;ti0=c; }
        else if (v > tv1) { tv3=tv2;ti3=ti2; tv2=tv1;ti2=ti1; tv1=v;ti1=c; }
        else if (v > tv2) { tv3=tv2;ti3=ti2; tv2=v;ti2=c; }
        else              { tv3=v;ti3=c; }
      }
    }
  }

  unsigned long long deadm = 0ull;
  int ncons = 0;
  float bvs[8]; int bis[8];
#pragma unroll
  for (int it = 0; it < 8; ++it) {
    float bv = tv0; int bi = ti0;
#pragma unroll
    for (int mm = 1; mm <= 8; mm <<= 1) {
      float ov = __shfl_xor(bv, mm, 64);
      int   oi = __shfl_xor(bi, mm, 64);
      if (ov > bv || (ov == bv && oi < bi)) { bv = ov; bi = oi; }
    }
    bvs[it] = bv; bis[it] = bi;
    if (bv > -1e29f && (((bi >> 2) & 15) == l15)) {  // this lane owned the winner
      deadm |= 1ull << (((bi >> 6) << 2) | (bi & 3));
      tv0=tv1;ti0=ti1; tv1=tv2;ti1=ti2; tv2=tv3;ti2=ti3;
      tv3=-1e38f; ti3=0x40000000;
      if (++ncons == 4) {                            // cache exhausted: rebuild (rare)
        ncons = 0;
        tv0=tv1=tv2=tv3=-1e38f;
        ti0=ti1=ti2=ti3=0x40000000;
        for (int j = 0; j < jmaxB; ++j) {
          int cb = j * 64 + l15 * 4;
          float4 vv = *(const float4*)(srow + cb);
          float xs[4] = {vv.x, vv.y, vv.z, vv.w};
#pragma unroll
          for (int e = 0; e < 4; ++e) {
            int c = cb + e;
            int li = ((c >> 6) << 2) | (c & 3);
            float v = (c < nv && !((deadm >> li) & 1ull)) ? xs[e] : -1e38f;
            if (v > tv3) {
              if (v > tv0)      { tv3=tv2;ti3=ti2; tv2=tv1;ti2=ti1; tv1=tv0;ti1=ti0; tv0=v;ti0=c; }
              else if (v > tv1) { tv3=tv2;ti3=ti2; tv2=tv1;ti2=ti1; tv1=v;ti1=c; }
              else if (v > tv2) { tv3=tv2;ti3=ti2; tv2=v;ti2=c; }
              else              { tv3=v;ti3=c; }
            }
          }
        }
      }
    }
  }

  // ---- gathers + softmax + output (16 lanes x 8 floats = 128 dims) ----
  const float m0 = bvs[0];
  float a0=0.f,a1=0.f,a2=0.f,a3=0.f,a4=0.f,a5=0.f,a6=0.f,a7=0.f;
  float esum = 0.f;
#pragma unroll
  for (int it = 0; it < 8; ++it) {
    if (bvs[it] > -1e29f) {
      float wgt = expf(bvs[it] - m0);
      esum += wgt;
      const float* cvp = ckvF + (size_t)bis[it] * 256 + 128 + l15 * 8;
      float4 u = *(const float4*)cvp;
      float4 v = *(const float4*)(cvp + 4);
      a0 += wgt*u.x; a1 += wgt*u.y; a2 += wgt*u.z; a3 += wgt*u.w;
      a4 += wgt*v.x; a5 += wgt*v.y; a6 += wgt*v.z; a7 += wgt*v.w;
    }
  }
  float inv = 1.0f / fmaxf(esum, 1e-9f);
  bf16* op = sp + (size_t)s * 2048 + (2 * by + p2) * 128 + l15 * 8;
  bf16 ob[8] = {__float2bfloat16(a0*inv), __float2bfloat16(a1*inv),
                __float2bfloat16(a2*inv), __float2bfloat16(a3*inv),
                __float2bfloat16(a4*inv), __float2bfloat16(a5*inv),
                __float2bfloat16(a6*inv), __float2bfloat16(a7*inv)};
  *(uint4*)op = *(uint4*)ob;
}

// ---------------- local sliding-window via MFMA ----------------
__global__ __launch_bounds__(128) void local_mfma(const float* __restrict__ qf,
                                                  const bf16* __restrict__ lklv,
                                                  const bf16* __restrict__ VT,
                                                  const bf16* __restrict__ sp,
                                                  bf16* __restrict__ merged) {
  constexpr int PADP = 168;
  __shared__ bf16 PhS[2][16 * PADP];
  __shared__ bf16 PlS[2][16 * PADP];
  const int h = blockIdx.y;
  const int t = threadIdx.x, w = t >> 6, lane = t & 63;
  const int quad = lane >> 4, l15 = lane & 15;
  const int sw = blockIdx.x * 32 + w * 16;
  const int kbase = sw - 128;
  const int ridx = quad * 4;

  bf16x8 qH[4], qL[4];
  {
    const float* qp = qf + (size_t)(sw + l15) * HID_ + h * 128 + quad * 8;
#pragma unroll
    for (int kk = 0; kk < 4; ++kk) {
      float4 u = *(const float4*)(qp + kk * 32);
      float4 v = *(const float4*)(qp + kk * 32 + 4);
      float xs[8] = {u.x, u.y, u.z, u.w, v.x, v.y, v.z, v.w};
      bf16x8 hh, ll;
#pragma unroll
      for (int e = 0; e < 8; ++e) {
        bf16 bh = __float2bfloat16(xs[e]);
        float fh = __bfloat162float(bh);
        bf16 bl = __float2bfloat16(xs[e] - fh);
        hh[e] = bf2s(bh); ll[e] = bf2s(bl);
      }
      qH[kk] = hh; qL[kk] = ll;
    }
  }

  float sc[9][4];
#pragma unroll
  for (int ct = 0; ct < 9; ++ct) {
    int key0 = kbase + ct * 16 + l15;
    const bf16* kp = lklv + (size_t)(key0 < 0 ? 0 : key0) * 4096 + h * 128 + quad * 8;
    f32x4 acc = {0.f, 0.f, 0.f, 0.f};
#pragma unroll
    for (int kk = 0; kk < 4; ++kk) {
      bf16x8 kb = *(const bf16x8*)(kp + kk * 32);
      acc = __builtin_amdgcn_mfma_f32_16x16x32_bf16(qL[kk], kb, acc, 0, 0, 0);
      acc = __builtin_amdgcn_mfma_f32_16x16x32_bf16(qH[kk], kb, acc, 0, 0, 0);
    }
#pragma unroll
    for (int r = 0; r < 4; ++r) sc[ct][r] = acc[r] * SCALE_;
  }

  float mrow[4] = {-1e30f, -1e30f, -1e30f, -1e30f};
#pragma unroll
  for (int ct = 0; ct < 9; ++ct) {
    int cidx = ct * 16 + l15;
#pragma unroll
    for (int r = 0; r < 4; ++r) {
      bool valid = (cidx >= ridx + r) && (cidx <= ridx + r + 128) && (kbase + cidx >= 0);
      float v = valid ? sc[ct][r] : -1e30f;
      sc[ct][r] = v;
      mrow[r] = fmaxf(mrow[r], v);
    }
  }
#pragma unroll
  for (int mm = 1; mm <= 8; mm <<= 1)
#pragma unroll
    for (int r = 0; r < 4; ++r) mrow[r] = fmaxf(mrow[r], __shfl_xor(mrow[r], mm, 64));

  bf16* phb = &PhS[w][0];
  bf16* plb = &PlS[w][0];
  for (int z = lane; z < 256; z += 64) {
    int zr = z >> 4, zc = z & 15;
    phb[zr * PADP + 144 + zc] = __float2bfloat16(0.f);
    plb[zr * PADP + 144 + zc] = __float2bfloat16(0.f);
  }
  float lsum[4] = {0.f, 0.f, 0.f, 0.f};
#pragma unroll
  for (int ct = 0; ct < 9; ++ct) {
    int cidx = ct * 16 + l15;
#pragma unroll
    for (int r = 0; r < 4; ++r) {
      float e = (sc[ct][r] > -1e29f) ? expf(sc[ct][r] - mrow[r]) : 0.f;
      lsum[r] += e;
      bf16 bh = __float2bfloat16(e);
      float fh = __bfloat162float(bh);
      bf16 bl = __float2bfloat16(e - fh);
      phb[(ridx + r) * PADP + cidx] = bh;
      plb[(ridx + r) * PADP + cidx] = bl;
    }
  }
#pragma unroll
  for (int mm = 1; mm <= 8; mm <<= 1)
#pragma unroll
    for (int r = 0; r < 4; ++r) lsum[r] += __shfl_xor(lsum[r], mm, 64);
  float inv[4];
#pragma unroll
  for (int r = 0; r < 4; ++r) inv[r] = 1.0f / lsum[r];

  bf16x8 pH[5], pL[5];
#pragma unroll
  for (int kk = 0; kk < 5; ++kk) {
    pH[kk] = *(const bf16x8*)(phb + l15 * PADP + kk * 32 + quad * 8);
    pL[kk] = *(const bf16x8*)(plb + l15 * PADP + kk * 32 + quad * 8);
  }

#pragma unroll
  for (int dt = 0; dt < 8; ++dt) {
    const bf16* vrow = VT + (size_t)(h * 128 + dt * 16 + l15) * 4096;
    f32x4 acc = {0.f, 0.f, 0.f, 0.f};
#pragma unroll
    for (int kk = 0; kk < 5; ++kk) {
      int ko = kbase + kk * 32 + quad * 8;
      ko = ko < 0 ? 0 : (ko > 4088 ? 4088 : ko);
      bf16x8 vb = *(const bf16x8*)(vrow + ko);
      acc = __builtin_amdgcn_mfma_f32_16x16x32_bf16(pL[kk], vb, acc, 0, 0, 0);
      acc = __builtin_amdgcn_mfma_f32_16x16x32_bf16(pH[kk], vb, acc, 0, 0, 0);
    }
#pragma unroll
    for (int r = 0; r < 4; ++r) {
      int srow = sw + ridx + r;
      size_t off = (size_t)srow * 2048 + h * 128 + dt * 16 + l15;
      float spv = __bfloat162float(sp[off]);
      merged[off] = __float2bfloat16((acc[r] * inv[r] + spv) * 0.5f);
    }
  }
}

// ---------------- host orchestration ----------------
extern "C" void kernel_launch(void* const* d_in, const int* in_sizes, int n_in,
                              void* d_out, int out_size, void* d_ws, size_t ws_size,
                              hipStream_t stream) {
  (void)in_sizes; (void)n_in; (void)out_size; (void)ws_size;
  const float* hidden = (const float*)d_in[0];
  const float* Wq   = (const float*)d_in[1];
  const float* bq   = (const float*)d_in[2];
  const float* Wcmp = (const float*)d_in[3];
  const float* bcmp = (const float*)d_in[4];
  const float* Wk   = (const float*)d_in[5];
  const float* bk   = (const float*)d_in[6];
  const float* Wv   = (const float*)d_in[7];
  const float* bv   = (const float*)d_in[8];
  const float* Wlk  = (const float*)d_in[9];
  const float* blk  = (const float*)d_in[10];
  const float* Wlv  = (const float*)d_in[11];
  const float* blv  = (const float*)d_in[12];
  const float* qn_w = (const float*)d_in[13];
  const float* kn_w = (const float*)d_in[14];
  const float* Wo   = (const float*)d_in[15];
  const float* bo   = (const float*)d_in[16];
  float* out = (float*)d_out;

  // workspace (~155 MB). Overlays: qh over WqTs (dead after q gemm), merged over hbf,
  // sp over bt_lklv (both dead after lklv gemm), VT over qh (dead after sparse_v9).
  char* ws = (char*)d_ws;
  float*    qf       = (float*)   (ws);                  // 33,554,432
  bf16*     lklv     = (bf16*)    (ws + 33554432);       // 33,554,432
  float*    WqTs     = (float*)   (ws + 67108864);       // 16,777,216 (x1024)
  _Float16* qh       = (_Float16*)(ws + 67108864);       // overlay of WqTs
  bf16*     VT       = (bf16*)    (ws + 67108864);       // overlay of qh: lv^T [2048][4096]
  bf16*     hbf      = (bf16*)    (ws + 83886080);       // 16,777,216
  bf16*     merged   = (bf16*)    (ws + 83886080);       // overlay of hbf
  bf16*     bt_lklv  = (bf16*)    (ws + 100663296);      // 16,777,216
  bf16*     sp       = (bf16*)    (ws + 100663296);      // overlay of bt_lklv
  float*    WkvTs    = (float*)   (ws + 117440512);      //  2,097,152 (x1024)
  bf16*     WoT      = (bf16*)    (ws + 119537664);      //  8,388,608
  float*    entriesF = (float*)   (ws + 127926272);      //  8,388,608
  float*    ckvF     = (float*)   (ws + 136314880);      //  1,048,576
  _Float16* ckh      = (_Float16*)(ws + 137363456);      //    262,144
  _Float16* ckl      = (_Float16*)(ws + 137625600);      //    262,144
  float*    wlog     = (float*)   (ws + 137887744);      //     16,384
  float*    wsm      = (float*)   (ws + 137904128);      //     16,384
  float*    bQ       = (float*)   (ws + 137920512);      //      8,192
  float*    bLKLV    = (float*)   (ws + 137928704);      //     16,384
  float*    bKV      = (float*)   (ws + 137945088);      //      1,024
  float*    bO       = (float*)   (ws + 137946112);      //      8,192
  _Float16* ql       = (_Float16*)(ws + 137954304);      // 16,777,216  (end ~154.7 MB)

  cvt_k<<<dim3(8192), dim3(256), 0, stream>>>(hidden, hbf);

  trans_f32s<<<dim3(32, 32), dim3(256), 0, stream>>>(Wq, WqTs, HID_, HID_);
  trans_f32s<<<dim3(2, 32),  dim3(256), 0, stream>>>(Wk, WkvTs, HID_, 128);
  trans_f32s<<<dim3(2, 32),  dim3(256), 0, stream>>>(Wv, WkvTs + (size_t)128 * HID_, HID_, 128);
  transpose_k<<<dim3(32, 32), dim3(256), 0, stream>>>(Wlk, bt_lklv, HID_, HID_);
  transpose_k<<<dim3(32, 32), dim3(256), 0, stream>>>(Wlv, bt_lklv + (size_t)2048 * HID_, HID_, HID_);
  transpose_k<<<dim3(32, 32), dim3(256), 0, stream>>>(Wo, WoT, HID_, HID_);
  build_bias<<<dim3(33), dim3(256), 0, stream>>>(bq, blk, blv, bk, bv, bo, bQ, bLKLV, bKV, bO);

  wlog_k<<<dim3(1024), dim3(256), 0, stream>>>(hidden, Wcmp, bcmp, wlog);
  wsm_k<<<dim3(4), dim3(256), 0, stream>>>(wlog, wsm);
  entries_k<<<dim3(8192), dim3(256), 0, stream>>>(hidden, wsm, entriesF);

  // precise projections
  gemm_prec4<<<dim3(16, 32), dim3(256), 0, stream>>>(hidden,   WqTs,  bQ,  qf,   S_LEN, HID_, HID_, HID_);
  gemm_prec4<<<dim3(2, 8),   dim3(256), 0, stream>>>(entriesF, WkvTs, bKV, ckvF, C_,    256,  HID_, HID_);
  // smooth lk|lv projection (bf16)
  gemm_bt<bf16><<<dim3(32, 32), dim3(256), 0, stream>>>(hbf, bt_lklv, bLKLV, lklv, S_LEN, 4096, HID_, HID_);

  // norms + rope
  normrope64<<<dim3(16384), dim3(256), 0, stream>>>(qf,   qn_w, 65536, 16, HID_, 1, 0);
  normrope64<<<dim3(256),   dim3(256), 0, stream>>>(ckvF, kn_w, 1024,  1,  256,  4, 3);
  normrope_bf<<<dim3(16384), dim3(256), 0, stream>>>(lklv, kn_w, 65536, 16, 4096);

  // pre-split operands for sparse scores (after norms/rope; qh safely overlays dead WqTs)
  split_q_k<<<dim3(8192), dim3(256), 0, stream>>>(qf, qh, ql);
  split_ck_k<<<dim3(512), dim3(256), 0, stream>>>(ckvF, ckh, ckl);

  // sparse branch first (consumes qh), then transpose lv into VT (overlays qh)
  sparse_v9<<<dim3(512, 8), dim3(1024), 0, stream>>>(qh, ql, ckh, ckl, ckvF, sp);
  trans_v_k<<<dim3(64, 32), dim3(256), 0, stream>>>(lklv, VT);
  local_mfma<<<dim3(128, 16), dim3(128), 0, stream>>>(qf, lklv, VT, sp, merged);

  // output projection
  gemm_bt<float><<<dim3(16, 32), dim3(256), 0, stream>>>(merged, WoT, bO, out, S_LEN, HID_, HID_, HID_);
}

// Round 5
// 1107.714 us; speedup vs baseline: 1.2214x; 1.0516x over previous
//
#include <hip/hip_runtime.h>
#include <hip/hip_bf16.h>
#include <hip/hip_fp16.h>
#include <stdint.h>

typedef __hip_bfloat16 bf16;
using bf16x8 = __attribute__((ext_vector_type(8))) short;     // 8 bf16
using half8  = __attribute__((ext_vector_type(8))) _Float16;  // 8 fp16
using f32x4  = __attribute__((ext_vector_type(4))) float;

#define S_LEN   4096
#define HID_    2048
#define NH_     16
#define D_      128
#define C_      1024
#define SCALE_  0.08838834764831845f   // 1/sqrt(128)
#define DESC_   (1.0 / 1048576.0)      // 2^-20 (undo ×1024 on both operands)

__device__ __forceinline__ float bflo(uint32_t u) {
  uint32_t x = (u & 0xffffu) << 16; float f; __builtin_memcpy(&f, &x, 4); return f;
}
__device__ __forceinline__ float bfhi(uint32_t u) {
  uint32_t x = u & 0xffff0000u; float f; __builtin_memcpy(&f, &x, 4); return f;
}
__device__ __forceinline__ void storeC(float* p, float v) { *p = v; }
__device__ __forceinline__ void storeC(bf16* p, float v)  { *p = __float2bfloat16(v); }
__device__ __forceinline__ void split2(float x, _Float16& h, _Float16& l) {
  h = (_Float16)x; l = (_Float16)(x - (float)h);
}
__device__ __forceinline__ short bf2s(bf16 b) { short s; __builtin_memcpy(&s, &b, 2); return s; }

// ---------------- fp32 -> bf16 convert (hidden) ----------------
__global__ __launch_bounds__(256) void cvt_k(const float* __restrict__ src, bf16* __restrict__ dst) {
  int i = (blockIdx.x * 256 + threadIdx.x) * 4;
  float4 v = *(const float4*)(src + i);
  bf16 o[4] = {__float2bfloat16(v.x), __float2bfloat16(v.y),
               __float2bfloat16(v.z), __float2bfloat16(v.w)};
  *(uint2*)(dst + i) = *(uint2*)o;
}

// ---------------- ck split: ckvF rows (stride 256, first 128 cols) -> [c][k] fp16 hi/lo ----------------
__global__ __launch_bounds__(256) void split_ck_k(const float* __restrict__ ckvF,
                                                  _Float16* __restrict__ oh, _Float16* __restrict__ ol) {
  int idx = blockIdx.x * 256 + threadIdx.x;     // c*128 + k, total 131072
  int c = idx >> 7, k = idx & 127;
  float x = ckvF[(size_t)c * 256 + k] * 1024.0f;
  _Float16 h, l; split2(x, h, l);
  oh[idx] = h; ol[idx] = l;
}

// ---------------- transpose: fp32 (R x N) -> bf16 (N x R) ----------------
__global__ __launch_bounds__(256) void transpose_k(const float* __restrict__ src,
                                                   bf16* __restrict__ dst, int R, int N) {
  __shared__ float tile[64][65];
  const int c0 = blockIdx.x * 64, r0 = blockIdx.y * 64;
  const int t = threadIdx.x, cc = t & 63, rb = t >> 6;
#pragma unroll
  for (int i = 0; i < 16; ++i) {
    int r = rb + i * 4;
    tile[r][cc] = src[(size_t)(r0 + r) * N + c0 + cc];
  }
  __syncthreads();
#pragma unroll
  for (int i = 0; i < 16; ++i) {
    int r = rb + i * 4;
    dst[(size_t)(c0 + r) * R + r0 + cc] = __float2bfloat16(tile[cc][r]);
  }
}

// ---------------- transpose: fp32 (R x N) -> fp32 (N x R), prescaled x1024 ----------------
__global__ __launch_bounds__(256) void trans_f32s(const float* __restrict__ src,
                                                  float* __restrict__ dst, int R, int N) {
  __shared__ float tile[64][65];
  const int c0 = blockIdx.x * 64, r0 = blockIdx.y * 64;
  const int t = threadIdx.x, cc = t & 63, rb = t >> 6;
#pragma unroll
  for (int i = 0; i < 16; ++i) {
    int r = rb + i * 4;
    tile[r][cc] = src[(size_t)(r0 + r) * N + c0 + cc];
  }
  __syncthreads();
#pragma unroll
  for (int i = 0; i < 16; ++i) {
    int r = rb + i * 4;
    dst[(size_t)(c0 + r) * R + r0 + cc] = tile[cc][r] * 1024.0f;
  }
}

// ---------------- transpose lv half of lklv (bf16 [4096][2048-slice]) -> VT [2048][4096] ----------------
__global__ __launch_bounds__(256) void trans_v_k(const bf16* __restrict__ lklv, bf16* __restrict__ VT) {
  __shared__ ushort tile[64][65];
  const int s0 = blockIdx.x * 64, c0 = blockIdx.y * 64;  // c indexes h*128+d in [0,2048)
  const int t = threadIdx.x, cc = t & 63, rb = t >> 6;
  const ushort* src = (const ushort*)lklv;
#pragma unroll
  for (int i = 0; i < 16; ++i) {
    int r = rb + i * 4;
    tile[r][cc] = src[(size_t)(s0 + r) * 4096 + 2048 + c0 + cc];
  }
  __syncthreads();
  ushort* dst = (ushort*)VT;
#pragma unroll
  for (int i = 0; i < 16; ++i) {
    int r = rb + i * 4;
    dst[(size_t)(c0 + r) * 4096 + s0 + cc] = tile[cc][r];
  }
}

// ---------------- bias concat ----------------
__global__ void build_bias(const float* bq, const float* blk, const float* blv,
                           const float* bk, const float* bv, const float* bo,
                           float* bQ, float* bLKLV, float* bKV, float* bO) {
  int i = blockIdx.x * 256 + threadIdx.x;
  if (i < 2048)       bQ[i] = bq[i];
  else if (i < 6144)  { int j = i - 2048; bLKLV[j] = (j < 2048) ? blk[j] : blv[j - 2048]; }
  else if (i < 6400)  { int j = i - 6144; bKV[j] = (j < 128) ? bk[j] : bv[j - 128]; }
  else if (i < 8448)  bO[i - 6400] = bo[i - 6400];
}

// ---------------- plain m97-style bf16 GEMM ----------------
template <typename OutT>
__global__ __launch_bounds__(256) void gemm_bt(const bf16* __restrict__ A, const bf16* __restrict__ BT,
                                               const float* __restrict__ bias, OutT* __restrict__ Cmat,
                                               int M, int N, int K, int lda) {
  __shared__ bf16 As[128 * 32];
  __shared__ bf16 Bs[128 * 32];
  const int t = threadIdx.x;
  const int wave = t >> 6, lane = t & 63;
  const int wr = wave >> 1, wc = wave & 1;
  const int quad = lane >> 4, l15 = lane & 15;
  const int bx = blockIdx.x * 128, by = blockIdx.y * 128;
  const int srow = t >> 2, scol = (t & 3) * 8;
  f32x4 acc[4][4] = {};
  const bf16* a0 = A + (size_t)(by + srow) * lda + scol;
  const bf16* a1 = A + (size_t)(by + 64 + srow) * lda + scol;
  const bf16* b0 = BT + (size_t)(bx + srow) * K + scol;
  const bf16* b1 = BT + (size_t)(bx + 64 + srow) * K + scol;
  for (int k0 = 0; k0 < K; k0 += 32) {
    __builtin_amdgcn_global_load_lds((const __attribute__((address_space(1))) void*)(a0 + k0),
                                     (__attribute__((address_space(3))) void*)(As + t * 8), 16, 0, 0);
    __builtin_amdgcn_global_load_lds((const __attribute__((address_space(1))) void*)(a1 + k0),
                                     (__attribute__((address_space(3))) void*)(As + 2048 + t * 8), 16, 0, 0);
    __builtin_amdgcn_global_load_lds((const __attribute__((address_space(1))) void*)(b0 + k0),
                                     (__attribute__((address_space(3))) void*)(Bs + t * 8), 16, 0, 0);
    __builtin_amdgcn_global_load_lds((const __attribute__((address_space(1))) void*)(b1 + k0),
                                     (__attribute__((address_space(3))) void*)(Bs + 2048 + t * 8), 16, 0, 0);
    __syncthreads();
    bf16x8 aF[4], bF[4];
#pragma unroll
    for (int i = 0; i < 4; ++i)
      aF[i] = *(const bf16x8*)(As + (wr * 64 + i * 16 + l15) * 32 + quad * 8);
#pragma unroll
    for (int j = 0; j < 4; ++j)
      bF[j] = *(const bf16x8*)(Bs + (wc * 64 + j * 16 + l15) * 32 + quad * 8);
#pragma unroll
    for (int i = 0; i < 4; ++i)
#pragma unroll
      for (int j = 0; j < 4; ++j)
        acc[i][j] = __builtin_amdgcn_mfma_f32_16x16x32_bf16(aF[i], bF[j], acc[i][j], 0, 0, 0);
    __syncthreads();
  }
#pragma unroll
  for (int i = 0; i < 4; ++i)
#pragma unroll
    for (int j = 0; j < 4; ++j)
#pragma unroll
      for (int r = 0; r < 4; ++r) {
        int row = by + wr * 64 + i * 16 + quad * 4 + r;
        int col = bx + wc * 64 + j * 16 + l15;
        storeC(&Cmat[(size_t)row * N + col], acc[i][j][r] + bias[col]);
      }
}

// ---------------- precise GEMM: fp16 2-way split, 4 MFMA terms, fp64 per-kstep accum ----------------
__global__ __launch_bounds__(256) void gemm_prec4(const float* __restrict__ A, const float* __restrict__ BT,
                                                  const float* __restrict__ bias, float* __restrict__ Cmat,
                                                  int M, int N, int K, int lda) {
  __shared__ _Float16 Ah[128 * 32], Al[128 * 32], Bh[128 * 32], Bl[128 * 32];
  const int t = threadIdx.x;
  const int wave = t >> 6, lane = t & 63;
  const int wr = wave >> 1, wc = wave & 1;
  const int quad = lane >> 4, l15 = lane & 15;
  const int bx = blockIdx.x * 128, by = blockIdx.y * 128;
  double acc[4][4][4] = {};
  for (int k0 = 0; k0 < K; k0 += 32) {
#pragma unroll
    for (int it = 0; it < 4; ++it) {
      int sl = t + it * 256;
      int isB = sl >> 9, s2 = sl & 511, r = s2 >> 2, g = s2 & 3;
      const float* src = isB ? (BT + (size_t)(bx + r) * K + k0 + g * 8)
                             : (A  + (size_t)(by + r) * lda + k0 + g * 8);
      float4 u = ((const float4*)src)[0];
      float4 v = ((const float4*)src)[1];
      float xs[8] = {u.x, u.y, u.z, u.w, v.x, v.y, v.z, v.w};
      half8 hh, ll;
#pragma unroll
      for (int e = 0; e < 8; ++e) {
        float x = isB ? xs[e] : xs[e] * 1024.0f;
        _Float16 h, l; split2(x, h, l);
        hh[e] = h; ll[e] = l;
      }
      _Float16* dh = (isB ? Bh : Ah) + r * 32 + g * 8;
      _Float16* dl = (isB ? Bl : Al) + r * 32 + g * 8;
      *(half8*)dh = hh;
      *(half8*)dl = ll;
    }
    __syncthreads();
    half8 aFh[4], aFl[4], bFh[4], bFl[4];
#pragma unroll
    for (int i = 0; i < 4; ++i) {
      int ro = (wr * 64 + i * 16 + l15) * 32 + quad * 8;
      aFh[i] = *(const half8*)(Ah + ro);
      aFl[i] = *(const half8*)(Al + ro);
    }
#pragma unroll
    for (int j = 0; j < 4; ++j) {
      int ro = (wc * 64 + j * 16 + l15) * 32 + quad * 8;
      bFh[j] = *(const half8*)(Bh + ro);
      bFl[j] = *(const half8*)(Bl + ro);
    }
#pragma unroll
    for (int i = 0; i < 4; ++i)
#pragma unroll
      for (int j = 0; j < 4; ++j) {
        f32x4 tt = {0.f, 0.f, 0.f, 0.f};
        tt = __builtin_amdgcn_mfma_f32_16x16x32_f16(aFl[i], bFl[j], tt, 0, 0, 0);
        tt = __builtin_amdgcn_mfma_f32_16x16x32_f16(aFl[i], bFh[j], tt, 0, 0, 0);
        tt = __builtin_amdgcn_mfma_f32_16x16x32_f16(aFh[i], bFl[j], tt, 0, 0, 0);
        tt = __builtin_amdgcn_mfma_f32_16x16x32_f16(aFh[i], bFh[j], tt, 0, 0, 0);
#pragma unroll
        for (int r = 0; r < 4; ++r) acc[i][j][r] += (double)tt[r];
      }
    __syncthreads();
  }
#pragma unroll
  for (int i = 0; i < 4; ++i)
#pragma unroll
    for (int j = 0; j < 4; ++j)
#pragma unroll
      for (int r = 0; r < 4; ++r) {
        int row = by + wr * 64 + i * 16 + quad * 4 + r;
        int col = bx + wc * 64 + j * 16 + l15;
        Cmat[(size_t)row * N + col] = (float)(acc[i][j][r] * DESC_ + (double)bias[col]);
      }
}

// ---------------- fp64 rmsnorm + fp32-faithful rope (generic, used for ckv only) ----------------
__global__ __launch_bounds__(256) void normrope64(float* __restrict__ base, const float* __restrict__ w,
                                                  int nRows, int hPerS, int sStride,
                                                  int posMul, int posAdd) {
  int row = blockIdx.x * 4 + (threadIdx.x >> 6);
  int lane = threadIdx.x & 63;
  if (row >= nRows) return;
  int s = row / hPerS, h = row - s * hPerS;
  float* p = base + (size_t)s * sStride + h * 128;
  double x0 = (double)p[lane];
  double x1 = (double)p[lane + 64];
  double ss = x0 * x0 + x1 * x1;
#pragma unroll
  for (int m = 32; m; m >>= 1) ss += __shfl_xor(ss, m, 64);
  double rstd = 1.0 / sqrt(ss * (1.0 / 128.0) + 1e-6);
  double n0 = x0 * rstd * (double)w[lane];
  double n1 = x1 * rstd * (double)w[lane + 64];
  double other = __shfl_xor(n0, 32, 64);
  int fi = lane & 31;
  float invf = 1.0f / (float)pow(10000.0, (double)fi * (1.0 / 32.0));
  float angf = (float)(s * posMul + posAdd) * invf;
  double ang = (double)angf;
  double cs = cos(ang), sn = sin(ang);
  double r0 = (lane < 32) ? (n0 * cs - other * sn) : (other * sn + n0 * cs);
  p[lane] = (float)r0;
  p[lane + 64] = (float)n1;
}

// ---------------- fp64 rmsnorm + rope for q: one block per s, trig shared across 16 heads ----------------
// Bit-identical math to normrope64(posMul=1,posAdd=0) + split_q_k fused into the epilogue.
__global__ __launch_bounds__(256) void normrope64_q(float* __restrict__ base, const float* __restrict__ w,
                                                    _Float16* __restrict__ qh, _Float16* __restrict__ ql) {
  __shared__ double csd[32], snd[32];
  const int s = blockIdx.x;
  const int t = threadIdx.x, wv = t >> 6, lane = t & 63;
  if (t < 32) {
    float invf = 1.0f / (float)pow(10000.0, (double)t * (1.0 / 32.0));
    float angf = (float)s * invf;
    double ang = (double)angf;
    csd[t] = cos(ang);
    snd[t] = sin(ang);
  }
  __syncthreads();
  const int fi = lane & 31;
  float* ps = base + (size_t)s * HID_;
  for (int h = wv; h < 16; h += 4) {
    float* p = ps + h * 128;
    double x0 = (double)p[lane];
    double x1 = (double)p[lane + 64];
    double ss = x0 * x0 + x1 * x1;
#pragma unroll
    for (int m = 32; m; m >>= 1) ss += __shfl_xor(ss, m, 64);
    double rstd = 1.0 / sqrt(ss * (1.0 / 128.0) + 1e-6);
    double n0 = x0 * rstd * (double)w[lane];
    double n1 = x1 * rstd * (double)w[lane + 64];
    double other = __shfl_xor(n0, 32, 64);
    double cs = csd[fi], sn = snd[fi];
    double r0 = (lane < 32) ? (n0 * cs - other * sn) : (other * sn + n0 * cs);
    float f0 = (float)r0, f1 = (float)n1;
    p[lane] = f0;
    p[lane + 64] = f1;
    // fused hi/lo fp16 split (x1024) — identical to split_q_k on the rounded floats
    _Float16 h0, l0, h1, l1;
    split2(f0 * 1024.0f, h0, l0);
    split2(f1 * 1024.0f, h1, l1);
    size_t off = (size_t)s * HID_ + h * 128;
    qh[off + lane] = h0;       ql[off + lane] = l0;
    qh[off + 64 + lane] = h1;  ql[off + 64 + lane] = l1;
  }
}

// ---------------- bf16 rmsnorm+rope for lk: one block per s, trig shared across 16 heads ----------------
__global__ __launch_bounds__(256) void normrope_bf_l(bf16* __restrict__ base, const float* __restrict__ w) {
  __shared__ float csf[32], snf[32];
  const int s = blockIdx.x;
  const int t = threadIdx.x, wv = t >> 6, lane = t & 63;
  if (t < 32) {
    float invf = 1.0f / (float)pow(10000.0, (double)t * (1.0 / 32.0));
    float ang = (float)s * invf;
    csf[t] = cosf(ang);
    snf[t] = sinf(ang);
  }
  __syncthreads();
  const int fi = lane & 31;
  bf16* ps = base + (size_t)s * 4096;
  for (int h = wv; h < 16; h += 4) {
    bf16* p = ps + h * 128;
    float x0 = __bfloat162float(p[lane]);
    float x1 = __bfloat162float(p[lane + 64]);
    float ss = x0 * x0 + x1 * x1;
#pragma unroll
    for (int m = 32; m; m >>= 1) ss += __shfl_xor(ss, m, 64);
    float rstd = rsqrtf(ss * 0.0078125f + 1e-6f);
    float n0 = x0 * rstd * w[lane];
    float n1 = x1 * rstd * w[lane + 64];
    float other = __shfl_xor(n0, 32, 64);
    float cs = csf[fi], sn = snf[fi];
    float r0 = (lane < 32) ? (n0 * cs - other * sn) : (other * sn + n0 * cs);
    p[lane] = __float2bfloat16(r0);
    p[lane + 64] = __float2bfloat16(n1);
  }
}

// ---------------- compress logits (fp64) ----------------
__global__ __launch_bounds__(256) void wlog_k(const float* __restrict__ hidden, const float* __restrict__ wcmp,
                                              const float* __restrict__ bcmp, float* __restrict__ wlog) {
  int s = blockIdx.x * 4 + (threadIdx.x >> 6);
  int lane = threadIdx.x & 63;
  const float* hp = hidden + (size_t)s * HID_;
  double acc = 0.0;
  for (int i = lane; i < HID_; i += 64)
    acc += (double)hp[i] * (double)wcmp[i];
#pragma unroll
  for (int m = 32; m; m >>= 1) acc += __shfl_xor(acc, m, 64);
  if (lane == 0) wlog[s] = (float)(acc + (double)bcmp[0]);
}

__global__ void wsm_k(const float* __restrict__ wlog, float* __restrict__ wsm) {
  int c = blockIdx.x * 256 + threadIdx.x;
  if (c >= C_) return;
  double v[4], m = -1e300;
#pragma unroll
  for (int r = 0; r < 4; ++r) { v[r] = (double)wlog[4 * c + r]; if (v[r] > m) m = v[r]; }
  double sum = 0.0;
#pragma unroll
  for (int r = 0; r < 4; ++r) { v[r] = exp(v[r] - m); sum += v[r]; }
#pragma unroll
  for (int r = 0; r < 4; ++r) wsm[4 * c + r] = (float)(v[r] / sum);
}

__global__ __launch_bounds__(256) void entries_k(const float* __restrict__ hidden, const float* __restrict__ wsm,
                                                 float* __restrict__ entriesF) {
  int idx = blockIdx.x * 256 + threadIdx.x;     // c*2048 + hcol
  int c = idx >> 11, hcol = idx & 2047;
  double e = 0.0;
#pragma unroll
  for (int r = 0; r < 4; ++r)
    e += (double)wsm[4 * c + r] * (double)hidden[(size_t)(4 * c + r) * HID_ + hcol];
  entriesF[idx] = (float)e;
}

// ---------------- sparse v9: phase 1 as v8 (16 waves); phase 2 on 16-lane groups ----------------
__global__ __launch_bounds__(1024, 8) void sparse_v9(const _Float16* __restrict__ qh, const _Float16* __restrict__ ql,
                                                     const _Float16* __restrict__ ckh, const _Float16* __restrict__ ckl,
                                                     const float* __restrict__ ckvF, bf16* __restrict__ sp) {
  __shared__ float sc[16 * 1024];               // 64 KB -> 2 blocks/CU
  const int by = blockIdx.y;                    // head pair: heads 2*by, 2*by+1
  const int s0 = blockIdx.x * 8;
  const int t = threadIdx.x, w = t >> 6, lane = t & 63;
  const int quad = lane >> 4, l15 = lane & 15;
  const int nvmax  = (s0 >> 2) + 2;             // max causally valid blocks for s in [s0,s0+8)
  const int ntiles = (nvmax + 15) >> 4;
  const double esc = (double)SCALE_ * DESC_;

  // ---- phase 1: score tiles distributed over 16 waves (A rows = 16 (q,h) chains) ----
  if (w < ntiles) {
    const int sA = s0 + (l15 & 7);
    const int hA = 2 * by + (l15 >> 3);
    half8 aFh[4], aFl[4];
    {
      const _Float16* qbh = qh + (size_t)sA * HID_ + hA * 128 + quad * 8;
      const _Float16* qbl = ql + (size_t)sA * HID_ + hA * 128 + quad * 8;
#pragma unroll
      for (int kk = 0; kk < 4; ++kk) {
        aFh[kk] = *(const half8*)(qbh + kk * 32);
        aFl[kk] = *(const half8*)(qbl + kk * 32);
      }
    }
    for (int ct = w; ct < ntiles; ct += 16) {
      const int c0 = ct * 16;
      const _Float16* kbh = ckh + (size_t)(c0 + l15) * 128 + quad * 8;
      const _Float16* kbl = ckl + (size_t)(c0 + l15) * 128 + quad * 8;
      double a64[4] = {0.0, 0.0, 0.0, 0.0};
#pragma unroll
      for (int kk = 0; kk < 4; ++kk) {
        half8 bh = *(const half8*)(kbh + kk * 32);
        half8 bl = *(const half8*)(kbl + kk * 32);
        f32x4 tt = {0.f, 0.f, 0.f, 0.f};
        tt = __builtin_amdgcn_mfma_f32_16x16x32_f16(aFl[kk], bl, tt, 0, 0, 0);
        tt = __builtin_amdgcn_mfma_f32_16x16x32_f16(aFl[kk], bh, tt, 0, 0, 0);
        tt = __builtin_amdgcn_mfma_f32_16x16x32_f16(aFh[kk], bl, tt, 0, 0, 0);
        tt = __builtin_amdgcn_mfma_f32_16x16x32_f16(aFh[kk], bh, tt, 0, 0, 0);
#pragma unroll
        for (int r = 0; r < 4; ++r) a64[r] += (double)tt[r];
      }
#pragma unroll
      for (int r = 0; r < 4; ++r)
        sc[(quad * 4 + r) * 1024 + c0 + l15] = (float)(a64[r] * esc);
    }
  }
  __syncthreads();
  if (w >= 4) return;

  // ---- phase 2: chain q = w*4 + quad, handled by 16 lanes (l15) ----
  const int q = w * 4 + quad;                   // == row in sc
  const int p2 = q >> 3, wq = q & 7;
  const int s = s0 + wq;
  const int nv = (s >= 3) ? (((s - 3) >> 2) + 1) : 0;
  const float* srow = sc + q * 1024;
  const int jmaxB = (nvmax + 63) >> 6;          // block-uniform j-tile count (1..16)

  // per-lane top-4 cache (tv[0] best; stable: ascending c, strict >)
  float tv0 = -1e38f, tv1 = -1e38f, tv2 = -1e38f, tv3 = -1e38f;
  int   ti0 = 0x40000000, ti1 = 0x40000000, ti2 = 0x40000000, ti3 = 0x40000000;
  for (int j = 0; j < jmaxB; ++j) {
    int cb = j * 64 + l15 * 4;
    float4 vv = *(const float4*)(srow + cb);
    float xs[4] = {vv.x, vv.y, vv.z, vv.w};
#pragma unroll
    for (int e = 0; e < 4; ++e) {
      int c = cb + e;
      float v = (c < nv) ? xs[e] : -1e38f;
      if (v > tv3) {
        if (v > tv0)      { tv3=tv2;ti3=ti2; tv2=tv1;ti2=ti1; tv1=tv0;ti1=ti0; tv0=v;ti0=c; }
        else if (v > tv1) { tv3=tv2;ti3=ti2; tv2=tv1;ti2=ti1; tv1=v;ti1=c; }
        else if (v > tv2) { tv3=tv2;ti3=ti2; tv2=v;ti2=c; }
        else              { tv3=v;ti3=c; }
      }
    }
  }

  unsigned long long deadm = 0ull;
  int ncons = 0;
  float bvs[8]; int bis[8];
#pragma unroll
  for (int it = 0; it < 8; ++it) {
    float bv = tv0; int bi = ti0;
#pragma unroll
    for (int mm = 1; mm <= 8; mm <<= 1) {
      float ov = __shfl_xor(bv, mm, 64);
      int   oi = __shfl_xor(bi, mm, 64);
      if (ov > bv || (ov == bv && oi < bi)) { bv = ov; bi = oi; }
    }
    bvs[it] = bv; bis[it] = bi;
    if (bv > -1e29f && (((bi >> 2) & 15) == l15)) {  // this lane owned the winner
      deadm |= 1ull << (((bi >> 6) << 2) | (bi & 3));
      tv0=tv1;ti0=ti1; tv1=tv2;ti1=ti2; tv2=tv3;ti2=ti3;
      tv3=-1e38f; ti3=0x40000000;
      if (++ncons == 4) {                            // cache exhausted: rebuild (rare)
        ncons = 0;
        tv0=tv1=tv2=tv3=-1e38f;
        ti0=ti1=ti2=ti3=0x40000000;
        for (int j = 0; j < jmaxB; ++j) {
          int cb = j * 64 + l15 * 4;
          float4 vv = *(const float4*)(srow + cb);
          float xs[4] = {vv.x, vv.y, vv.z, vv.w};
#pragma unroll
          for (int e = 0; e < 4; ++e) {
            int c = cb + e;
            int li = ((c >> 6) << 2) | (c & 3);
            float v = (c < nv && !((deadm >> li) & 1ull)) ? xs[e] : -1e38f;
            if (v > tv3) {
              if (v > tv0)      { tv3=tv2;ti3=ti2; tv2=tv1;ti2=ti1; tv1=tv0;ti1=ti0; tv0=v;ti0=c; }
              else if (v > tv1) { tv3=tv2;ti3=ti2; tv2=tv1;ti2=ti1; tv1=v;ti1=c; }
              else if (v > tv2) { tv3=tv2;ti3=ti2; tv2=v;ti2=c; }
              else              { tv3=v;ti3=c; }
            }
          }
        }
      }
    }
  }

  // ---- gathers + softmax + output (16 lanes x 8 floats = 128 dims) ----
  const float m0 = bvs[0];
  float a0=0.f,a1=0.f,a2=0.f,a3=0.f,a4=0.f,a5=0.f,a6=0.f,a7=0.f;
  float esum = 0.f;
#pragma unroll
  for (int it = 0; it < 8; ++it) {
    if (bvs[it] > -1e29f) {
      float wgt = expf(bvs[it] - m0);
      esum += wgt;
      const float* cvp = ckvF + (size_t)bis[it] * 256 + 128 + l15 * 8;
      float4 u = *(const float4*)cvp;
      float4 v = *(const float4*)(cvp + 4);
      a0 += wgt*u.x; a1 += wgt*u.y; a2 += wgt*u.z; a3 += wgt*u.w;
      a4 += wgt*v.x; a5 += wgt*v.y; a6 += wgt*v.z; a7 += wgt*v.w;
    }
  }
  float inv = 1.0f / fmaxf(esum, 1e-9f);
  bf16* op = sp + (size_t)s * 2048 + (2 * by + p2) * 128 + l15 * 8;
  bf16 ob[8] = {__float2bfloat16(a0*inv), __float2bfloat16(a1*inv),
                __float2bfloat16(a2*inv), __float2bfloat16(a3*inv),
                __float2bfloat16(a4*inv), __float2bfloat16(a5*inv),
                __float2bfloat16(a6*inv), __float2bfloat16(a7*inv)};
  *(uint4*)op = *(uint4*)ob;
}

// ---------------- local sliding-window via MFMA ----------------
__global__ __launch_bounds__(128) void local_mfma(const float* __restrict__ qf,
                                                  const bf16* __restrict__ lklv,
                                                  const bf16* __restrict__ VT,
                                                  const bf16* __restrict__ sp,
                                                  bf16* __restrict__ merged) {
  constexpr int PADP = 168;
  __shared__ bf16 PhS[2][16 * PADP];
  __shared__ bf16 PlS[2][16 * PADP];
  const int h = blockIdx.y;
  const int t = threadIdx.x, w = t >> 6, lane = t & 63;
  const int quad = lane >> 4, l15 = lane & 15;
  const int sw = blockIdx.x * 32 + w * 16;
  const int kbase = sw - 128;
  const int ridx = quad * 4;

  bf16x8 qH[4], qL[4];
  {
    const float* qp = qf + (size_t)(sw + l15) * HID_ + h * 128 + quad * 8;
#pragma unroll
    for (int kk = 0; kk < 4; ++kk) {
      float4 u = *(const float4*)(qp + kk * 32);
      float4 v = *(const float4*)(qp + kk * 32 + 4);
      float xs[8] = {u.x, u.y, u.z, u.w, v.x, v.y, v.z, v.w};
      bf16x8 hh, ll;
#pragma unroll
      for (int e = 0; e < 8; ++e) {
        bf16 bh = __float2bfloat16(xs[e]);
        float fh = __bfloat162float(bh);
        bf16 bl = __float2bfloat16(xs[e] - fh);
        hh[e] = bf2s(bh); ll[e] = bf2s(bl);
      }
      qH[kk] = hh; qL[kk] = ll;
    }
  }

  float sc[9][4];
#pragma unroll
  for (int ct = 0; ct < 9; ++ct) {
    int key0 = kbase + ct * 16 + l15;
    const bf16* kp = lklv + (size_t)(key0 < 0 ? 0 : key0) * 4096 + h * 128 + quad * 8;
    f32x4 acc = {0.f, 0.f, 0.f, 0.f};
#pragma unroll
    for (int kk = 0; kk < 4; ++kk) {
      bf16x8 kb = *(const bf16x8*)(kp + kk * 32);
      acc = __builtin_amdgcn_mfma_f32_16x16x32_bf16(qL[kk], kb, acc, 0, 0, 0);
      acc = __builtin_amdgcn_mfma_f32_16x16x32_bf16(qH[kk], kb, acc, 0, 0, 0);
    }
#pragma unroll
    for (int r = 0; r < 4; ++r) sc[ct][r] = acc[r] * SCALE_;
  }

  float mrow[4] = {-1e30f, -1e30f, -1e30f, -1e30f};
#pragma unroll
  for (int ct = 0; ct < 9; ++ct) {
    int cidx = ct * 16 + l15;
#pragma unroll
    for (int r = 0; r < 4; ++r) {
      bool valid = (cidx >= ridx + r) && (cidx <= ridx + r + 128) && (kbase + cidx >= 0);
      float v = valid ? sc[ct][r] : -1e30f;
      sc[ct][r] = v;
      mrow[r] = fmaxf(mrow[r], v);
    }
  }
#pragma unroll
  for (int mm = 1; mm <= 8; mm <<= 1)
#pragma unroll
    for (int r = 0; r < 4; ++r) mrow[r] = fmaxf(mrow[r], __shfl_xor(mrow[r], mm, 64));

  bf16* phb = &PhS[w][0];
  bf16* plb = &PlS[w][0];
  for (int z = lane; z < 256; z += 64) {
    int zr = z >> 4, zc = z & 15;
    phb[zr * PADP + 144 + zc] = __float2bfloat16(0.f);
    plb[zr * PADP + 144 + zc] = __float2bfloat16(0.f);
  }
  float lsum[4] = {0.f, 0.f, 0.f, 0.f};
#pragma unroll
  for (int ct = 0; ct < 9; ++ct) {
    int cidx = ct * 16 + l15;
#pragma unroll
    for (int r = 0; r < 4; ++r) {
      float e = (sc[ct][r] > -1e29f) ? expf(sc[ct][r] - mrow[r]) : 0.f;
      lsum[r] += e;
      bf16 bh = __float2bfloat16(e);
      float fh = __bfloat162float(bh);
      bf16 bl = __float2bfloat16(e - fh);
      phb[(ridx + r) * PADP + cidx] = bh;
      plb[(ridx + r) * PADP + cidx] = bl;
    }
  }
#pragma unroll
  for (int mm = 1; mm <= 8; mm <<= 1)
#pragma unroll
    for (int r = 0; r < 4; ++r) lsum[r] += __shfl_xor(lsum[r], mm, 64);
  float inv[4];
#pragma unroll
  for (int r = 0; r < 4; ++r) inv[r] = 1.0f / lsum[r];

  bf16x8 pH[5], pL[5];
#pragma unroll
  for (int kk = 0; kk < 5; ++kk) {
    pH[kk] = *(const bf16x8*)(phb + l15 * PADP + kk * 32 + quad * 8);
    pL[kk] = *(const bf16x8*)(plb + l15 * PADP + kk * 32 + quad * 8);
  }

#pragma unroll
  for (int dt = 0; dt < 8; ++dt) {
    const bf16* vrow = VT + (size_t)(h * 128 + dt * 16 + l15) * 4096;
    f32x4 acc = {0.f, 0.f, 0.f, 0.f};
#pragma unroll
    for (int kk = 0; kk < 5; ++kk) {
      int ko = kbase + kk * 32 + quad * 8;
      ko = ko < 0 ? 0 : (ko > 4088 ? 4088 : ko);
      bf16x8 vb = *(const bf16x8*)(vrow + ko);
      acc = __builtin_amdgcn_mfma_f32_16x16x32_bf16(pL[kk], vb, acc, 0, 0, 0);
      acc = __builtin_amdgcn_mfma_f32_16x16x32_bf16(pH[kk], vb, acc, 0, 0, 0);
    }
#pragma unroll
    for (int r = 0; r < 4; ++r) {
      int srow = sw + ridx + r;
      size_t off = (size_t)srow * 2048 + h * 128 + dt * 16 + l15;
      float spv = __bfloat162float(sp[off]);
      merged[off] = __float2bfloat16((acc[r] * inv[r] + spv) * 0.5f);
    }
  }
}

// ---------------- host orchestration ----------------
extern "C" void kernel_launch(void* const* d_in, const int* in_sizes, int n_in,
                              void* d_out, int out_size, void* d_ws, size_t ws_size,
                              hipStream_t stream) {
  (void)in_sizes; (void)n_in; (void)out_size; (void)ws_size;
  const float* hidden = (const float*)d_in[0];
  const float* Wq   = (const float*)d_in[1];
  const float* bq   = (const float*)d_in[2];
  const float* Wcmp = (const float*)d_in[3];
  const float* bcmp = (const float*)d_in[4];
  const float* Wk   = (const float*)d_in[5];
  const float* bk   = (const float*)d_in[6];
  const float* Wv   = (const float*)d_in[7];
  const float* bv   = (const float*)d_in[8];
  const float* Wlk  = (const float*)d_in[9];
  const float* blk  = (const float*)d_in[10];
  const float* Wlv  = (const float*)d_in[11];
  const float* blv  = (const float*)d_in[12];
  const float* qn_w = (const float*)d_in[13];
  const float* kn_w = (const float*)d_in[14];
  const float* Wo   = (const float*)d_in[15];
  const float* bo   = (const float*)d_in[16];
  float* out = (float*)d_out;

  // workspace (~155 MB). Overlays: qh over WqTs (dead after q gemm), merged over hbf,
  // sp over bt_lklv (both dead after lklv gemm), VT over qh (dead after sparse_v9).
  char* ws = (char*)d_ws;
  float*    qf       = (float*)   (ws);                  // 33,554,432
  bf16*     lklv     = (bf16*)    (ws + 33554432);       // 33,554,432
  float*    WqTs     = (float*)   (ws + 67108864);       // 16,777,216 (x1024)
  _Float16* qh       = (_Float16*)(ws + 67108864);       // overlay of WqTs
  bf16*     VT       = (bf16*)    (ws + 67108864);       // overlay of qh: lv^T [2048][4096]
  bf16*     hbf      = (bf16*)    (ws + 83886080);       // 16,777,216
  bf16*     merged   = (bf16*)    (ws + 83886080);       // overlay of hbf
  bf16*     bt_lklv  = (bf16*)    (ws + 100663296);      // 16,777,216
  bf16*     sp       = (bf16*)    (ws + 100663296);      // overlay of bt_lklv
  float*    WkvTs    = (float*)   (ws + 117440512);      //  2,097,152 (x1024)
  bf16*     WoT      = (bf16*)    (ws + 119537664);      //  8,388,608
  float*    entriesF = (float*)   (ws + 127926272);      //  8,388,608
  float*    ckvF     = (float*)   (ws + 136314880);      //  1,048,576
  _Float16* ckh      = (_Float16*)(ws + 137363456);      //    262,144
  _Float16* ckl      = (_Float16*)(ws + 137625600);      //    262,144
  float*    wlog     = (float*)   (ws + 137887744);      //     16,384
  float*    wsm      = (float*)   (ws + 137904128);      //     16,384
  float*    bQ       = (float*)   (ws + 137920512);      //      8,192
  float*    bLKLV    = (float*)   (ws + 137928704);      //     16,384
  float*    bKV      = (float*)   (ws + 137945088);      //      1,024
  float*    bO       = (float*)   (ws + 137946112);      //      8,192
  _Float16* ql       = (_Float16*)(ws + 137954304);      // 16,777,216  (end ~154.7 MB)

  cvt_k<<<dim3(8192), dim3(256), 0, stream>>>(hidden, hbf);

  trans_f32s<<<dim3(32, 32), dim3(256), 0, stream>>>(Wq, WqTs, HID_, HID_);
  trans_f32s<<<dim3(2, 32),  dim3(256), 0, stream>>>(Wk, WkvTs, HID_, 128);
  trans_f32s<<<dim3(2, 32),  dim3(256), 0, stream>>>(Wv, WkvTs + (size_t)128 * HID_, HID_, 128);
  transpose_k<<<dim3(32, 32), dim3(256), 0, stream>>>(Wlk, bt_lklv, HID_, HID_);
  transpose_k<<<dim3(32, 32), dim3(256), 0, stream>>>(Wlv, bt_lklv + (size_t)2048 * HID_, HID_, HID_);
  transpose_k<<<dim3(32, 32), dim3(256), 0, stream>>>(Wo, WoT, HID_, HID_);
  build_bias<<<dim3(33), dim3(256), 0, stream>>>(bq, blk, blv, bk, bv, bo, bQ, bLKLV, bKV, bO);

  wlog_k<<<dim3(1024), dim3(256), 0, stream>>>(hidden, Wcmp, bcmp, wlog);
  wsm_k<<<dim3(4), dim3(256), 0, stream>>>(wlog, wsm);
  entries_k<<<dim3(8192), dim3(256), 0, stream>>>(hidden, wsm, entriesF);

  // precise projections
  gemm_prec4<<<dim3(16, 32), dim3(256), 0, stream>>>(hidden,   WqTs,  bQ,  qf,   S_LEN, HID_, HID_, HID_);
  gemm_prec4<<<dim3(2, 8),   dim3(256), 0, stream>>>(entriesF, WkvTs, bKV, ckvF, C_,    256,  HID_, HID_);
  // smooth lk|lv projection (bf16)
  gemm_bt<bf16><<<dim3(32, 32), dim3(256), 0, stream>>>(hbf, bt_lklv, bLKLV, lklv, S_LEN, 4096, HID_, HID_);

  // norms + rope (q: trig shared across heads, fp16 split fused; qh overlays dead WqTs)
  normrope64_q<<<dim3(4096), dim3(256), 0, stream>>>(qf, qn_w, qh, ql);
  normrope64<<<dim3(256),   dim3(256), 0, stream>>>(ckvF, kn_w, 1024, 1, 256, 4, 3);
  normrope_bf_l<<<dim3(4096), dim3(256), 0, stream>>>(lklv, kn_w);

  // pre-split ck operands for sparse scores (after ckv norm/rope)
  split_ck_k<<<dim3(512), dim3(256), 0, stream>>>(ckvF, ckh, ckl);

  // sparse branch first (consumes qh), then transpose lv into VT (overlays qh)
  sparse_v9<<<dim3(512, 8), dim3(1024), 0, stream>>>(qh, ql, ckh, ckl, ckvF, sp);
  trans_v_k<<<dim3(64, 32), dim3(256), 0, stream>>>(lklv, VT);
  local_mfma<<<dim3(128, 16), dim3(128), 0, stream>>>(qf, lklv, VT, sp, merged);

  // output projection
  gemm_bt<float><<<dim3(16, 32), dim3(256), 0, stream>>>(merged, WoT, bO, out, S_LEN, HID_, HID_, HID_);
}